// Round 9
// baseline (266.644 us; speedup 1.0000x reference)
//
#include <hip/hip_runtime.h>
#include <math.h>

#define NB 8
#define NC 128
#define NP 96
#define ND 128
#define NH 8
#define NR 16

typedef __attribute__((ext_vector_type(8))) short short8;
typedef __attribute__((ext_vector_type(4))) float f32x4;
typedef __attribute__((ext_vector_type(4))) unsigned u32x4;

#define MFMA(a, b, c) __builtin_amdgcn_mfma_f32_16x16x32_bf16((a), (b), (c), 0, 0, 0)

__device__ __forceinline__ short8 s8(u32x4 u) { return __builtin_bit_cast(short8, u); }

// scalar fp32 -> bf16 (RNE) and back
__device__ __forceinline__ unsigned bfh_u(float x) {
  unsigned u = __float_as_uint(x);
  unsigned r = u + 0x7fffu + ((u >> 16) & 1u);
  return r >> 16;  // bf16 bits in low 16
}
__device__ __forceinline__ short bfh(float x) { return (short)bfh_u(x); }
__device__ __forceinline__ float bff(short s) {
  return __uint_as_float(((unsigned)(unsigned short)s) << 16);
}

// pair split: {hi_packed, lo_packed}, elem a in low 16 bits of each word
__device__ __forceinline__ uint2 split2(float a, float b) {
  unsigned ha = bfh_u(a), hb = bfh_u(b);
  float fa = __uint_as_float(ha << 16), fb = __uint_as_float(hb << 16);
  unsigned la = bfh_u(a - fa), lb = bfh_u(b - fb);
  return make_uint2(ha | (hb << 16), la | (lb << 16));
}

// split 8 consecutive floats into hi/lo packed u32x4
__device__ __forceinline__ void split8(const float4 x0, const float4 x1,
                                       u32x4* hi, u32x4* lo) {
  uint2 r0 = split2(x0.x, x0.y), r1 = split2(x0.z, x0.w);
  uint2 r2 = split2(x1.x, x1.y), r3 = split2(x1.z, x1.w);
  *hi = u32x4{r0.x, r1.x, r2.x, r3.x};
  *lo = u32x4{r0.y, r1.y, r2.y, r3.y};
}

// LDS row strides in shorts
#define TS_Z 136   // z      [rows][136]
#define TS_Q 72    // Q2     [rows][72]
#define TS_T 104   // zT/abar[rows][104]

#define W_ELEMS ((size_t)4 * 8 * 128 * 128)  // 524288 per split
#define W_NEED (W_ELEMS * 2 * 2)             // 2 MB

// ---------------- W split precompute: mats {tu, tv, cu, cv} ----------------
__global__ __launch_bounds__(256)
void prep_w(const float* __restrict__ w0, const float* __restrict__ w1,
            const float* __restrict__ w2, const float* __restrict__ w3,
            short* __restrict__ whi, short* __restrict__ wlo) {
  int t = blockIdx.x * 256 + threadIdx.x;   // 65536 threads, 8 elems each
  int mat = t >> 14;
  size_t off = (size_t)(t & 16383) * 8;
  const float* srcs[4] = {w0, w1, w2, w3};
  const float* s = srcs[mat] + off;
  u32x4 hi, lo;
  split8(*(const float4*)s, *(const float4*)(s + 4), &hi, &lo);
  size_t base = (size_t)mat * 131072 + off;
  *(u32x4*)&whi[base] = hi;
  *(u32x4*)&wlo[base] = lo;
}

// ---------------- time-message kernel: one block per (b,c) ----------------
// NOTE launch_bounds 2nd arg acts as min BLOCKS/CU on this toolchain
// (R6/R7/R8 evidence: cap = 2048/(arg*8 waves)). (512,2) -> 128-VGPR cap.
// LDS (79,872 B) caps residency at 2 blocks/CU anyway.
template <int WS>
__global__ __launch_bounds__(512, 2)
void tmsg_kernel(const float* __restrict__ qz, const float* __restrict__ wu,
                 const float* __restrict__ wv, const short* __restrict__ whi,
                 const short* __restrict__ wlo, float* __restrict__ out) {
  __shared__ __align__(16) short smem[39936];
  short* zhi = smem;                   // [96][136]
  short* zlo = smem + NP * TS_Z;
  short* qhi = smem + 2 * NP * TS_Z;   // [96][72]
  short* qlo = qhi + NP * TS_Q;
  short* zthi = smem;                  // [128][104] (phase2, aliased)
  short* ztlo = smem + ND * TS_T;
  short* ahi  = smem + 2 * ND * TS_T;  // [96][104]  (phase2)

  const int tid = threadIdx.x;
  const int l = tid & 63, w = tid >> 6;
  const int lm = l & 15, lk = l >> 4;
  const int c = blockIdx.x, b = blockIdx.y;
  const float* zg = qz + ((size_t)(b * NC + c) * NP) * ND;

  // ---- stage z -> split bf16 ----
  for (int i = tid; i < NP * 32; i += 512) {
    int p = i >> 5, s = i & 31;
    float4 v = ((const float4*)zg)[i];
    uint2 r0 = split2(v.x, v.y), r1 = split2(v.z, v.w);
    *(uint2*)&zhi[p * TS_Z + 4 * s] = make_uint2(r0.x, r1.x);
    *(uint2*)&zlo[p * TS_Z + 4 * s] = make_uint2(r0.y, r1.y);
  }
  __syncthreads();

  const int nt = w & 3, mset = (w >> 2) * 3;  // wave owns fixed nt, 3 m-tiles
  const int vsel = nt & 1, hsel = nt >> 1;
  const float qsc = vsel ? 1.0f : 0.25f;  // fold 1/sqrt(R) into Qu

  float aacc[4][6] = {};
  const short8 z8 = {0, 0, 0, 0, 0, 0, 0, 0};
  const f32x4 zf = {0.f, 0.f, 0.f, 0.f};

  for (int hp = 0; hp < 4; ++hp) {
    const int hd = 2 * hp + hsel;
    // ---- W fragments for this wave's nt ----
    u32x4 wbh[4], wbl[4];
    if constexpr (WS) {
      const size_t rb = (((size_t)vsel * 8 + b) * 128 + hd * NR + lm) * 128;
#pragma unroll
      for (int ks = 0; ks < 4; ++ks) {
        wbh[ks] = *(const u32x4*)&whi[rb + ks * 32 + lk * 8];
        wbl[ks] = *(const u32x4*)&wlo[rb + ks * 32 + lk * 8];
      }
    } else {
      const float* wrow = (vsel ? wv : wu) + ((size_t)b * ND + hd * NR + lm) * ND;
#pragma unroll
      for (int ks = 0; ks < 4; ++ks)
        split8(*(const float4*)(wrow + ks * 32 + lk * 8),
               *(const float4*)(wrow + ks * 32 + lk * 8 + 4), &wbh[ks], &wbl[ks]);
    }
    // ---- projection: Q tiles (m, nt) for m in mset..mset+2 ----
    f32x4 pacc[3] = {zf, zf, zf};
#pragma unroll
    for (int ks = 0; ks < 4; ++ks) {
#pragma unroll
      for (int mm = 0; mm < 3; ++mm) {
        int row = (mset + mm) * 16 + lm;
        short8 ah = *(const short8*)&zhi[row * TS_Z + ks * 32 + lk * 8];
        short8 al = *(const short8*)&zlo[row * TS_Z + ks * 32 + lk * 8];
        pacc[mm] = MFMA(ah, s8(wbh[ks]), pacc[mm]);
        pacc[mm] = MFMA(ah, s8(wbl[ks]), pacc[mm]);
        pacc[mm] = MFMA(al, s8(wbh[ks]), pacc[mm]);
      }
    }
#pragma unroll
    for (int mm = 0; mm < 3; ++mm) {
#pragma unroll
      for (int r = 0; r < 4; ++r) {
        float v = pacc[mm][r] * qsc;
        int row = (mset + mm) * 16 + lk * 4 + r, col = nt * 16 + lm;
        short hh = bfh(v);
        qhi[row * TS_Q + col] = hh;
        qlo[row * TS_Q + col] = bfh(v - bff(hh));
      }
    }
    __syncthreads();

    // ---- logits (K=16 zero-padded) + softmax (no max-sub); waves 0-5 ----
    if (w < 6) {
#pragma unroll
      for (int hh = 0; hh < 2; ++hh) {
        short8 ah = z8, al = z8;
        if (l < 32) {
          ah = *(const short8*)&qhi[(w * 16 + lm) * TS_Q + 32 * hh + lk * 8];
          al = *(const short8*)&qlo[(w * 16 + lm) * TS_Q + 32 * hh + lk * 8];
        }
        f32x4 s[6];
#pragma unroll
        for (int qt = 0; qt < 6; ++qt) {
          s[qt] = zf;
          short8 bh = z8, bl = z8;
          if (l < 32) {
            bh = *(const short8*)&qhi[(qt * 16 + lm) * TS_Q + 32 * hh + 16 + lk * 8];
            bl = *(const short8*)&qlo[(qt * 16 + lm) * TS_Q + 32 * hh + 16 + lk * 8];
          }
          s[qt] = MFMA(ah, bh, s[qt]);
          s[qt] = MFMA(ah, bl, s[qt]);
          s[qt] = MFMA(al, bh, s[qt]);
        }
#pragma unroll
        for (int r = 0; r < 4; ++r) {
          float e[6], sum = 0.f;
#pragma unroll
          for (int qt = 0; qt < 6; ++qt) { e[qt] = __expf(s[qt][r]); sum += e[qt]; }
          sum += __shfl_xor(sum, 1);
          sum += __shfl_xor(sum, 2);
          sum += __shfl_xor(sum, 4);
          sum += __shfl_xor(sum, 8);
          float inv = 1.0f / sum;
#pragma unroll
          for (int qt = 0; qt < 6; ++qt) aacc[r][qt] += e[qt] * inv;
        }
      }
    }
    __syncthreads();
  }

  // ---- phase2: build zT split + abar-hi in aliased LDS ----
  for (int i = tid; i < NP * 32; i += 512) {
    int p = i >> 5, s = i & 31;
    float4 v = ((const float4*)zg)[i];
    float f[4] = {v.x, v.y, v.z, v.w};
#pragma unroll
    for (int j = 0; j < 4; ++j) {
      int d = 4 * s + j;
      short hh = bfh(f[j]);
      zthi[d * TS_T + p] = hh;
      ztlo[d * TS_T + p] = bfh(f[j] - bff(hh));
    }
  }
  if (w < 6) {
#pragma unroll
    for (int r = 0; r < 4; ++r)
#pragma unroll
      for (int qt = 0; qt < 6; ++qt)
        ahi[(w * 16 + lk * 4 + r) * TS_T + qt * 16 + lm] = bfh(aacc[r][qt] * 0.125f);
  }
  __syncthreads();

  // ---- PV: m_t = abar @ z ; wave w owns d-tile w; K=96 ----
  float* og = out + ((size_t)(b * NC + c) * NP) * ND;
  f32x4 oacc[6] = {zf, zf, zf, zf, zf, zf};
#pragma unroll
  for (int ks = 0; ks < 3; ++ks) {
    short8 bh = *(const short8*)&zthi[(w * 16 + lm) * TS_T + ks * 32 + lk * 8];
    short8 bl = *(const short8*)&ztlo[(w * 16 + lm) * TS_T + ks * 32 + lk * 8];
#pragma unroll
    for (int m = 0; m < 6; ++m) {
      short8 a = *(const short8*)&ahi[(m * 16 + lm) * TS_T + ks * 32 + lk * 8];
      oacc[m] = MFMA(a, bh, oacc[m]);
      oacc[m] = MFMA(a, bl, oacc[m]);
    }
  }
#pragma unroll
  for (int m = 0; m < 6; ++m)
#pragma unroll
    for (int r = 0; r < 4; ++r)
      og[(m * 16 + lk * 4 + r) * ND + w * 16 + lm] = oacc[m][r];
}

// ---------------- channel-message kernel: one block per (b,p) ----------------
// z A-fragments in REGISTERS; LDS holds only Q (36,864 B).
// (512,2) -> 128-VGPR cap (2 blocks/CU, 16 waves/CU = 50% occ): fits the
// ~120-reg footprint with no spill. R8's (512,4) capped at 64 -> spilled.
template <int WS>
__global__ __launch_bounds__(512, 2)
void cmsg_kernel(const float* __restrict__ qz, const float* __restrict__ wu,
                 const float* __restrict__ wv, const short* __restrict__ whi,
                 const short* __restrict__ wlo, float* __restrict__ out) {
  __shared__ __align__(16) short qhi_s[NC * TS_Q];  // [128][72]
  __shared__ __align__(16) short qlo_s[NC * TS_Q];

  const int tid = threadIdx.x;
  const int l = tid & 63, w = tid >> 6;
  const int lm = l & 15, lk = l >> 4;
  const int p = blockIdx.x, b = blockIdx.y;

  // ---- z A-fragments for this wave's m-tile (rows w*16+lm), split in regs ----
  u32x4 zah[4], zal[4];
  {
    const float* zrow = qz + ((size_t)(b * NC + w * 16 + lm) * NP + p) * ND;
#pragma unroll
    for (int ks = 0; ks < 4; ++ks)
      split8(*(const float4*)(zrow + ks * 32 + lk * 8),
             *(const float4*)(zrow + ks * 32 + lk * 8 + 4), &zah[ks], &zal[ks]);
  }

  float aacc[4][8] = {};
  const short8 z8 = {0, 0, 0, 0, 0, 0, 0, 0};
  const f32x4 zf = {0.f, 0.f, 0.f, 0.f};

  for (int hp = 0; hp < 4; ++hp) {
    // ---- projection: wave w computes Q[m-tile w][all 4 nt] ----
#pragma unroll
    for (int nt = 0; nt < 4; ++nt) {
      const int vsel = nt & 1, hd = 2 * hp + (nt >> 1);
      u32x4 wbh[4], wbl[4];
      if constexpr (WS) {
        const size_t rb = (((size_t)(2 + vsel) * 8 + b) * 128 + hd * NR + lm) * 128;
#pragma unroll
        for (int ks = 0; ks < 4; ++ks) {
          wbh[ks] = *(const u32x4*)&whi[rb + ks * 32 + lk * 8];
          wbl[ks] = *(const u32x4*)&wlo[rb + ks * 32 + lk * 8];
        }
      } else {
        const float* wrow = (vsel ? wv : wu) + ((size_t)b * ND + hd * NR + lm) * ND;
#pragma unroll
        for (int ks = 0; ks < 4; ++ks)
          split8(*(const float4*)(wrow + ks * 32 + lk * 8),
                 *(const float4*)(wrow + ks * 32 + lk * 8 + 4), &wbh[ks], &wbl[ks]);
      }
      f32x4 pacc = zf;
#pragma unroll
      for (int ks = 0; ks < 4; ++ks) {
        pacc = MFMA(s8(zah[ks]), s8(wbh[ks]), pacc);
        pacc = MFMA(s8(zah[ks]), s8(wbl[ks]), pacc);
        pacc = MFMA(s8(zal[ks]), s8(wbh[ks]), pacc);
      }
      const float qsc = vsel ? 1.0f : 0.25f;
#pragma unroll
      for (int r = 0; r < 4; ++r) {
        float v = pacc[r] * qsc;
        int row = w * 16 + lk * 4 + r, col = nt * 16 + lm;
        short hh = bfh(v);
        qhi_s[row * TS_Q + col] = hh;
        qlo_s[row * TS_Q + col] = bfh(v - bff(hh));
      }
    }
    __syncthreads();

    // ---- logits (K=16 padded) + softmax over d' (no max-sub) ----
#pragma unroll
    for (int hh = 0; hh < 2; ++hh) {
      short8 ah = z8, al = z8;
      if (l < 32) {
        ah = *(const short8*)&qhi_s[(w * 16 + lm) * TS_Q + 32 * hh + lk * 8];
        al = *(const short8*)&qlo_s[(w * 16 + lm) * TS_Q + 32 * hh + lk * 8];
      }
      f32x4 s[8];
#pragma unroll
      for (int qt = 0; qt < 8; ++qt) {
        s[qt] = zf;
        short8 bh = z8, bl = z8;
        if (l < 32) {
          bh = *(const short8*)&qhi_s[(qt * 16 + lm) * TS_Q + 32 * hh + 16 + lk * 8];
          bl = *(const short8*)&qlo_s[(qt * 16 + lm) * TS_Q + 32 * hh + 16 + lk * 8];
        }
        s[qt] = MFMA(ah, bh, s[qt]);
        s[qt] = MFMA(ah, bl, s[qt]);
        s[qt] = MFMA(al, bh, s[qt]);
      }
#pragma unroll
      for (int r = 0; r < 4; ++r) {
        float e[8], sum = 0.f;
#pragma unroll
        for (int qt = 0; qt < 8; ++qt) { e[qt] = __expf(s[qt][r]); sum += e[qt]; }
        sum += __shfl_xor(sum, 1);
        sum += __shfl_xor(sum, 2);
        sum += __shfl_xor(sum, 4);
        sum += __shfl_xor(sum, 8);
        float inv = 1.0f / sum;
#pragma unroll
        for (int qt = 0; qt < 8; ++qt) aacc[r][qt] += e[qt] * inv;
      }
    }
    __syncthreads();
  }

  // ---- elementwise finish: m_c = (abar/8) * z, exact fp32 z from global ----
#pragma unroll
  for (int r = 0; r < 4; ++r) {
    int cc = w * 16 + lk * 4 + r;
    const float* zrow = qz + ((size_t)(b * NC + cc) * NP + p) * ND;
    float* orow = out + ((size_t)(b * NC + cc) * NP + p) * ND;
#pragma unroll
    for (int qt = 0; qt < 8; ++qt) {
      int d = qt * 16 + lm;
      orow[d] = 0.125f * aacc[r][qt] * zrow[d];
    }
  }
}

extern "C" void kernel_launch(void* const* d_in, const int* in_sizes, int n_in,
                              void* d_out, int out_size, void* d_ws, size_t ws_size,
                              hipStream_t stream) {
  const float* qz  = (const float*)d_in[0];
  const float* tuw = (const float*)d_in[1];
  const float* tvw = (const float*)d_in[2];
  const float* cuw = (const float*)d_in[3];
  const float* cvw = (const float*)d_in[4];
  float* out_t = (float*)d_out;
  float* out_c = out_t + (size_t)NB * NC * NP * ND;

  if (ws_size >= W_NEED) {
    short* whi = (short*)d_ws;
    short* wlo = whi + W_ELEMS;
    prep_w<<<256, 256, 0, stream>>>(tuw, tvw, cuw, cvw, whi, wlo);
    tmsg_kernel<1><<<dim3(NC, NB), 512, 0, stream>>>(qz, tuw, tvw, whi, wlo, out_t);
    cmsg_kernel<1><<<dim3(NP, NB), 512, 0, stream>>>(qz, cuw, cvw, whi, wlo, out_c);
  } else {
    tmsg_kernel<0><<<dim3(NC, NB), 512, 0, stream>>>(qz, tuw, tvw, nullptr, nullptr, out_t);
    cmsg_kernel<0><<<dim3(NP, NB), 512, 0, stream>>>(qz, cuw, cvw, nullptr, nullptr, out_c);
  }
}

// Round 12
// 208.985 us; speedup vs baseline: 1.2759x; 1.2759x over previous
//
#include <hip/hip_runtime.h>
#include <math.h>

#define NB 8
#define NC 128
#define NP 96
#define ND 128
#define NH 8
#define NR 16

typedef __attribute__((ext_vector_type(8))) short short8;
typedef __attribute__((ext_vector_type(4))) float f32x4;
typedef __attribute__((ext_vector_type(4))) unsigned u32x4;

#define MFMA(a, b, c) __builtin_amdgcn_mfma_f32_16x16x32_bf16((a), (b), (c), 0, 0, 0)

__device__ __forceinline__ short8 s8(u32x4 u) { return __builtin_bit_cast(short8, u); }

// scalar fp32 -> bf16 (RNE) and back
__device__ __forceinline__ unsigned bfh_u(float x) {
  unsigned u = __float_as_uint(x);
  unsigned r = u + 0x7fffu + ((u >> 16) & 1u);
  return r >> 16;
}
__device__ __forceinline__ short bfh(float x) { return (short)bfh_u(x); }
__device__ __forceinline__ float bff(short s) {
  return __uint_as_float(((unsigned)(unsigned short)s) << 16);
}

__device__ __forceinline__ uint2 split2(float a, float b) {
  unsigned ha = bfh_u(a), hb = bfh_u(b);
  float fa = __uint_as_float(ha << 16), fb = __uint_as_float(hb << 16);
  unsigned la = bfh_u(a - fa), lb = bfh_u(b - fb);
  return make_uint2(ha | (hb << 16), la | (lb << 16));
}

__device__ __forceinline__ void split8(const float4 x0, const float4 x1,
                                       u32x4* hi, u32x4* lo) {
  uint2 r0 = split2(x0.x, x0.y), r1 = split2(x0.z, x0.w);
  uint2 r2 = split2(x1.x, x1.y), r3 = split2(x1.z, x1.w);
  *hi = u32x4{r0.x, r1.x, r2.x, r3.x};
  *lo = u32x4{r0.y, r1.y, r2.y, r3.y};
}

// LDS row strides in shorts
#define TS_Z 136   // z      [rows][136]
#define TS_Q 72    // Q2     [rows][72]
#define TS_T 104   // zT/abar[rows][104]
#define TS_W 136   // W tile [16][136] per nt (2176 shorts per nt)

#define W_ELEMS ((size_t)4 * 8 * 128 * 128)  // 524288 per split
#define W_NEED (W_ELEMS * 2 * 2)             // 2 MB

// ---------------- W split precompute: mats {tu, tv, cu, cv} ----------------
__global__ __launch_bounds__(256)
void prep_w(const float* __restrict__ w0, const float* __restrict__ w1,
            const float* __restrict__ w2, const float* __restrict__ w3,
            short* __restrict__ whi, short* __restrict__ wlo) {
  int t = blockIdx.x * 256 + threadIdx.x;
  int mat = t >> 14;
  size_t off = (size_t)(t & 16383) * 8;
  const float* srcs[4] = {w0, w1, w2, w3};
  const float* s = srcs[mat] + off;
  u32x4 hi, lo;
  split8(*(const float4*)s, *(const float4*)(s + 4), &hi, &lo);
  size_t base = (size_t)mat * 131072 + off;
  *(u32x4*)&whi[base] = hi;
  *(u32x4*)&wlo[base] = lo;
}

// ================= time-message body: idx -> (b, c) =================
template <int WS>
__device__ __forceinline__ void tmsg_body(
    int idx, const float* __restrict__ qz, const float* __restrict__ wu,
    const float* __restrict__ wv, const short* __restrict__ whi,
    const short* __restrict__ wlo, float* __restrict__ out, short* smem) {
  short* zhi = smem;                   // [96][136]
  short* zlo = smem + NP * TS_Z;
  short* qhi = smem + 2 * NP * TS_Z;   // [96][72]
  short* qlo = qhi + NP * TS_Q;
  short* zthi = smem;                  // [128][104] (phase2, aliased)
  short* ztlo = smem + ND * TS_T;
  short* ahi  = smem + 2 * ND * TS_T;  // [96][104]  (phase2)

  const int tid = threadIdx.x;
  const int l = tid & 63, w = tid >> 6;
  const int lm = l & 15, lk = l >> 4;
  const int c = idx & 127, b = idx >> 7;
  const float* zg = qz + ((size_t)(b * NC + c) * NP) * ND;

  // ---- stage z -> split bf16 ----
  for (int i = tid; i < NP * 32; i += 512) {
    int p = i >> 5, s = i & 31;
    float4 v = ((const float4*)zg)[i];
    uint2 r0 = split2(v.x, v.y), r1 = split2(v.z, v.w);
    *(uint2*)&zhi[p * TS_Z + 4 * s] = make_uint2(r0.x, r1.x);
    *(uint2*)&zlo[p * TS_Z + 4 * s] = make_uint2(r0.y, r1.y);
  }
  __syncthreads();

  const int nt = w & 3, mset = (w >> 2) * 3;
  const int vsel = nt & 1, hsel = nt >> 1;
  const float qsc = vsel ? 1.0f : 0.25f;

  float aacc[4][6] = {};
  const short8 z8 = {0, 0, 0, 0, 0, 0, 0, 0};
  const f32x4 zf = {0.f, 0.f, 0.f, 0.f};

  for (int hp = 0; hp < 4; ++hp) {
    const int hd = 2 * hp + hsel;
    u32x4 wbh[4], wbl[4];
    if constexpr (WS) {
      const size_t rb = (((size_t)vsel * 8 + b) * 128 + hd * NR + lm) * 128;
#pragma unroll
      for (int ks = 0; ks < 4; ++ks) {
        wbh[ks] = *(const u32x4*)&whi[rb + ks * 32 + lk * 8];
        wbl[ks] = *(const u32x4*)&wlo[rb + ks * 32 + lk * 8];
      }
    } else {
      const float* wrow = (vsel ? wv : wu) + ((size_t)b * ND + hd * NR + lm) * ND;
#pragma unroll
      for (int ks = 0; ks < 4; ++ks)
        split8(*(const float4*)(wrow + ks * 32 + lk * 8),
               *(const float4*)(wrow + ks * 32 + lk * 8 + 4), &wbh[ks], &wbl[ks]);
    }
    f32x4 pacc[3] = {zf, zf, zf};
#pragma unroll
    for (int ks = 0; ks < 4; ++ks) {
#pragma unroll
      for (int mm = 0; mm < 3; ++mm) {
        int row = (mset + mm) * 16 + lm;
        short8 ah = *(const short8*)&zhi[row * TS_Z + ks * 32 + lk * 8];
        short8 al = *(const short8*)&zlo[row * TS_Z + ks * 32 + lk * 8];
        pacc[mm] = MFMA(ah, s8(wbh[ks]), pacc[mm]);
        pacc[mm] = MFMA(ah, s8(wbl[ks]), pacc[mm]);
        pacc[mm] = MFMA(al, s8(wbh[ks]), pacc[mm]);
      }
    }
#pragma unroll
    for (int mm = 0; mm < 3; ++mm) {
#pragma unroll
      for (int r = 0; r < 4; ++r) {
        float v = pacc[mm][r] * qsc;
        int row = (mset + mm) * 16 + lk * 4 + r, col = nt * 16 + lm;
        short hh = bfh(v);
        qhi[row * TS_Q + col] = hh;
        qlo[row * TS_Q + col] = bfh(v - bff(hh));
      }
    }
    __syncthreads();

    if (w < 6) {
#pragma unroll
      for (int hh = 0; hh < 2; ++hh) {
        short8 ah = z8, al = z8;
        if (l < 32) {
          ah = *(const short8*)&qhi[(w * 16 + lm) * TS_Q + 32 * hh + lk * 8];
          al = *(const short8*)&qlo[(w * 16 + lm) * TS_Q + 32 * hh + lk * 8];
        }
        f32x4 s[6];
#pragma unroll
        for (int qt = 0; qt < 6; ++qt) {
          s[qt] = zf;
          short8 bh = z8, bl = z8;
          if (l < 32) {
            bh = *(const short8*)&qhi[(qt * 16 + lm) * TS_Q + 32 * hh + 16 + lk * 8];
            bl = *(const short8*)&qlo[(qt * 16 + lm) * TS_Q + 32 * hh + 16 + lk * 8];
          }
          s[qt] = MFMA(ah, bh, s[qt]);
          s[qt] = MFMA(ah, bl, s[qt]);
          s[qt] = MFMA(al, bh, s[qt]);
        }
#pragma unroll
        for (int r = 0; r < 4; ++r) {
          float e[6], sum = 0.f;
#pragma unroll
          for (int qt = 0; qt < 6; ++qt) { e[qt] = __expf(s[qt][r]); sum += e[qt]; }
          sum += __shfl_xor(sum, 1);
          sum += __shfl_xor(sum, 2);
          sum += __shfl_xor(sum, 4);
          sum += __shfl_xor(sum, 8);
          float inv = 1.0f / sum;
#pragma unroll
          for (int qt = 0; qt < 6; ++qt) aacc[r][qt] += e[qt] * inv;
        }
      }
    }
    __syncthreads();
  }

  // ---- phase2: build zT split + abar-hi in aliased LDS ----
  for (int i = tid; i < NP * 32; i += 512) {
    int p = i >> 5, s = i & 31;
    float4 v = ((const float4*)zg)[i];
    float f[4] = {v.x, v.y, v.z, v.w};
#pragma unroll
    for (int j = 0; j < 4; ++j) {
      int d = 4 * s + j;
      short hh = bfh(f[j]);
      zthi[d * TS_T + p] = hh;
      ztlo[d * TS_T + p] = bfh(f[j] - bff(hh));
    }
  }
  if (w < 6) {
#pragma unroll
    for (int r = 0; r < 4; ++r)
#pragma unroll
      for (int qt = 0; qt < 6; ++qt)
        ahi[(w * 16 + lk * 4 + r) * TS_T + qt * 16 + lm] = bfh(aacc[r][qt] * 0.125f);
  }
  __syncthreads();

  // ---- PV: m_t = abar @ z ----
  float* og = out + ((size_t)(b * NC + c) * NP) * ND;
  f32x4 oacc[6] = {zf, zf, zf, zf, zf, zf};
#pragma unroll
  for (int ks = 0; ks < 3; ++ks) {
    short8 bh = *(const short8*)&zthi[(w * 16 + lm) * TS_T + ks * 32 + lk * 8];
    short8 bl = *(const short8*)&ztlo[(w * 16 + lm) * TS_T + ks * 32 + lk * 8];
#pragma unroll
    for (int m = 0; m < 6; ++m) {
      short8 a = *(const short8*)&ahi[(m * 16 + lm) * TS_T + ks * 32 + lk * 8];
      oacc[m] = MFMA(a, bh, oacc[m]);
      oacc[m] = MFMA(a, bl, oacc[m]);
    }
  }
#pragma unroll
  for (int m = 0; m < 6; ++m)
#pragma unroll
    for (int r = 0; r < 4; ++r)
      og[(m * 16 + lk * 4 + r) * ND + w * 16 + lm] = oacc[m][r];
}

// ================= channel-message body: idx -> (b, p) =================
// z in registers; W cooperatively staged in LDS per hp (kills the R9
// serialized per-wave W-load critical path); Q in LDS.
template <int WS>
__device__ __forceinline__ void cmsg_body(
    int idx, const float* __restrict__ qz, const float* __restrict__ wu,
    const float* __restrict__ wv, const short* __restrict__ whi,
    const short* __restrict__ wlo, float* __restrict__ out, short* smem) {
  short* qhi_s = smem;                       // [128][72] = 9216
  short* qlo_s = smem + NC * TS_Q;           // 9216
  short* wsthi = smem + 2 * NC * TS_Q;       // [4][16][136] = 8704
  short* wstlo = wsthi + 4 * 16 * TS_W;      // 8704   (total 35,840 shorts)

  const int tid = threadIdx.x;
  const int l = tid & 63, w = tid >> 6;
  const int lm = l & 15, lk = l >> 4;
  const int p = idx % 96, b = idx / 96;

  // ---- z A-fragments for this wave's m-tile, split in regs ----
  u32x4 zah[4], zal[4];
  {
    const float* zrow = qz + ((size_t)(b * NC + w * 16 + lm) * NP + p) * ND;
#pragma unroll
    for (int ks = 0; ks < 4; ++ks)
      split8(*(const float4*)(zrow + ks * 32 + lk * 8),
             *(const float4*)(zrow + ks * 32 + lk * 8 + 4), &zah[ks], &zal[ks]);
  }

  float aacc[4][8] = {};
  const short8 z8 = {0, 0, 0, 0, 0, 0, 0, 0};
  const f32x4 zf = {0.f, 0.f, 0.f, 0.f};

  for (int hp = 0; hp < 4; ++hp) {
    // ---- cooperative W stage for all 4 nt of this hp ----
    if constexpr (WS) {
      for (int ci = tid; ci < 2048; ci += 512) {
        int buf = ci >> 10, ix = ci & 1023;
        int nt = ix >> 8, row = (ix >> 4) & 15, colc = ix & 15;
        int vs = nt & 1, hd = 2 * hp + (nt >> 1);
        const short* src = (buf ? wlo : whi) +
            (((size_t)(2 + vs) * 8 + b) * 128 + hd * NR + row) * 128 + colc * 8;
        short* dst = (buf ? wstlo : wsthi) + nt * (16 * TS_W) + row * TS_W + colc * 8;
        *(u32x4*)dst = *(const u32x4*)src;
      }
    } else {
      for (int ci = tid; ci < 1024; ci += 512) {
        int nt = ci >> 8, row = (ci >> 4) & 15, colc = ci & 15;
        int vs = nt & 1, hd = 2 * hp + (nt >> 1);
        const float* src = (vs ? wv : wu) + ((size_t)b * ND + hd * NR + row) * ND + colc * 8;
        u32x4 hi, lo;
        split8(*(const float4*)src, *(const float4*)(src + 4), &hi, &lo);
        *(u32x4*)&wsthi[nt * (16 * TS_W) + row * TS_W + colc * 8] = hi;
        *(u32x4*)&wstlo[nt * (16 * TS_W) + row * TS_W + colc * 8] = lo;
      }
    }
    __syncthreads();  // W ready; also fences prior logits' Q reads

    // ---- projection: wave w computes Q[m-tile w][all 4 nt], W from LDS ----
#pragma unroll
    for (int nt = 0; nt < 4; ++nt) {
      f32x4 pacc = zf;
#pragma unroll
      for (int ks = 0; ks < 4; ++ks) {
        short8 bh = *(const short8*)&wsthi[nt * (16 * TS_W) + lm * TS_W + ks * 32 + lk * 8];
        short8 bl = *(const short8*)&wstlo[nt * (16 * TS_W) + lm * TS_W + ks * 32 + lk * 8];
        pacc = MFMA(s8(zah[ks]), bh, pacc);
        pacc = MFMA(s8(zah[ks]), bl, pacc);
        pacc = MFMA(s8(zal[ks]), bh, pacc);
      }
      const float qsc = (nt & 1) ? 1.0f : 0.25f;
#pragma unroll
      for (int r = 0; r < 4; ++r) {
        float v = pacc[r] * qsc;
        int row = w * 16 + lk * 4 + r, col = nt * 16 + lm;
        short hh = bfh(v);
        qhi_s[row * TS_Q + col] = hh;
        qlo_s[row * TS_Q + col] = bfh(v - bff(hh));
      }
    }
    __syncthreads();  // Q ready; proj's W reads done

    // ---- logits (K=16 padded) + softmax over d' (no max-sub) ----
#pragma unroll
    for (int hh = 0; hh < 2; ++hh) {
      short8 ah = z8, al = z8;
      if (l < 32) {
        ah = *(const short8*)&qhi_s[(w * 16 + lm) * TS_Q + 32 * hh + lk * 8];
        al = *(const short8*)&qlo_s[(w * 16 + lm) * TS_Q + 32 * hh + lk * 8];
      }
      f32x4 s[8];
#pragma unroll
      for (int qt = 0; qt < 8; ++qt) {
        s[qt] = zf;
        short8 bh = z8, bl = z8;
        if (l < 32) {
          bh = *(const short8*)&qhi_s[(qt * 16 + lm) * TS_Q + 32 * hh + 16 + lk * 8];
          bl = *(const short8*)&qlo_s[(qt * 16 + lm) * TS_Q + 32 * hh + 16 + lk * 8];
        }
        s[qt] = MFMA(ah, bh, s[qt]);
        s[qt] = MFMA(ah, bl, s[qt]);
        s[qt] = MFMA(al, bh, s[qt]);
      }
#pragma unroll
      for (int r = 0; r < 4; ++r) {
        float e[8], sum = 0.f;
#pragma unroll
        for (int qt = 0; qt < 8; ++qt) { e[qt] = __expf(s[qt][r]); sum += e[qt]; }
        sum += __shfl_xor(sum, 1);
        sum += __shfl_xor(sum, 2);
        sum += __shfl_xor(sum, 4);
        sum += __shfl_xor(sum, 8);
        float inv = 1.0f / sum;
#pragma unroll
        for (int qt = 0; qt < 8; ++qt) aacc[r][qt] += e[qt] * inv;
      }
    }
    // no barrier: next hp's W stage writes wst (disjoint from Q); its barrier
    // fences these Q reads before the next proj overwrites Q.
  }

  // ---- elementwise finish: m_c = (abar/8) * z ----
#pragma unroll
  for (int r = 0; r < 4; ++r) {
    int cc = w * 16 + lk * 4 + r;
    const float* zrow = qz + ((size_t)(b * NC + cc) * NP + p) * ND;
    float* orow = out + ((size_t)(b * NC + cc) * NP + p) * ND;
#pragma unroll
    for (int qt = 0; qt < 8; ++qt) {
      int d = qt * 16 + lm;
      orow[d] = 0.125f * aacc[r][qt] * zrow[d];
    }
  }
}

// ================= fused dispatcher =================
// 1792 blocks = 7 * 256; bid%7<4 -> tmsg (1024), else cmsg (768); interleaved
// so CUs host a mix of both workloads (overlapped stalls).
template <int WS>
__global__ __launch_bounds__(512, 2)
void fused_kernel(const float* __restrict__ qz, const float* __restrict__ tuw,
                  const float* __restrict__ tvw, const float* __restrict__ cuw,
                  const float* __restrict__ cvw, const short* __restrict__ whi,
                  const short* __restrict__ wlo, float* __restrict__ out_t,
                  float* __restrict__ out_c) {
  __shared__ __align__(16) short smem[39936];  // 79,872 B
  const int bid = blockIdx.x;
  const int r7 = bid % 7, q7 = bid / 7;
  if (r7 < 4)
    tmsg_body<WS>(q7 * 4 + r7, qz, tuw, tvw, whi, wlo, out_t, smem);
  else
    cmsg_body<WS>(q7 * 3 + (r7 - 4), qz, cuw, cvw, whi, wlo, out_c, smem);
}

extern "C" void kernel_launch(void* const* d_in, const int* in_sizes, int n_in,
                              void* d_out, int out_size, void* d_ws, size_t ws_size,
                              hipStream_t stream) {
  const float* qz  = (const float*)d_in[0];
  const float* tuw = (const float*)d_in[1];
  const float* tvw = (const float*)d_in[2];
  const float* cuw = (const float*)d_in[3];
  const float* cvw = (const float*)d_in[4];
  float* out_t = (float*)d_out;
  float* out_c = out_t + (size_t)NB * NC * NP * ND;

  if (ws_size >= W_NEED) {
    short* whi = (short*)d_ws;
    short* wlo = whi + W_ELEMS;
    prep_w<<<256, 256, 0, stream>>>(tuw, tvw, cuw, cvw, whi, wlo);
    fused_kernel<1><<<1792, 512, 0, stream>>>(qz, tuw, tvw, cuw, cvw, whi, wlo,
                                              out_t, out_c);
  } else {
    fused_kernel<0><<<1792, 512, 0, stream>>>(qz, tuw, tvw, cuw, cvw, nullptr,
                                              nullptr, out_t, out_c);
  }
}

// Round 13
// 184.438 us; speedup vs baseline: 1.4457x; 1.1331x over previous
//
#include <hip/hip_runtime.h>
#include <math.h>

#define NB 8
#define NC 128
#define NP 96
#define ND 128
#define NH 8
#define NR 16

typedef __attribute__((ext_vector_type(8))) short short8;
typedef __attribute__((ext_vector_type(4))) float f32x4;
typedef __attribute__((ext_vector_type(4))) unsigned u32x4;

#define MFMA(a, b, c) __builtin_amdgcn_mfma_f32_16x16x32_bf16((a), (b), (c), 0, 0, 0)

__device__ __forceinline__ short8 s8(u32x4 u) { return __builtin_bit_cast(short8, u); }

// scalar fp32 -> bf16 (RNE) and back
__device__ __forceinline__ unsigned bfh_u(float x) {
  unsigned u = __float_as_uint(x);
  unsigned r = u + 0x7fffu + ((u >> 16) & 1u);
  return r >> 16;
}
__device__ __forceinline__ short bfh(float x) { return (short)bfh_u(x); }
__device__ __forceinline__ float bff(short s) {
  return __uint_as_float(((unsigned)(unsigned short)s) << 16);
}

__device__ __forceinline__ uint2 split2(float a, float b) {
  unsigned ha = bfh_u(a), hb = bfh_u(b);
  float fa = __uint_as_float(ha << 16), fb = __uint_as_float(hb << 16);
  unsigned la = bfh_u(a - fa), lb = bfh_u(b - fb);
  return make_uint2(ha | (hb << 16), la | (lb << 16));
}

__device__ __forceinline__ void split8(const float4 x0, const float4 x1,
                                       u32x4* hi, u32x4* lo) {
  uint2 r0 = split2(x0.x, x0.y), r1 = split2(x0.z, x0.w);
  uint2 r2 = split2(x1.x, x1.y), r3 = split2(x1.z, x1.w);
  *hi = u32x4{r0.x, r1.x, r2.x, r3.x};
  *lo = u32x4{r0.y, r1.y, r2.y, r3.y};
}

// LDS row strides in shorts
#define TS_Z 136   // z      [rows][136]
#define TS_Q 72    // Q2     [rows][72]
#define TS_T 104   // zT/abar[rows][104]
#define TS_W 136   // W tile [16][136] per nt

#define W_ELEMS ((size_t)4 * 8 * 128 * 128)  // 524288 per split
#define W_NEED (W_ELEMS * 2 * 2)             // 2 MB

// ---------------- W split precompute: mats {tu, tv, cu, cv} ----------------
__global__ __launch_bounds__(256)
void prep_w(const float* __restrict__ w0, const float* __restrict__ w1,
            const float* __restrict__ w2, const float* __restrict__ w3,
            short* __restrict__ whi, short* __restrict__ wlo) {
  int t = blockIdx.x * 256 + threadIdx.x;
  int mat = t >> 14;
  size_t off = (size_t)(t & 16383) * 8;
  const float* srcs[4] = {w0, w1, w2, w3};
  const float* s = srcs[mat] + off;
  u32x4 hi, lo;
  split8(*(const float4*)s, *(const float4*)(s + 4), &hi, &lo);
  size_t base = (size_t)mat * 131072 + off;
  *(u32x4*)&whi[base] = hi;
  *(u32x4*)&wlo[base] = lo;
}

// ================= time-message body: idx -> (b, c) =================
template <int WS>
__device__ __forceinline__ void tmsg_body(
    int idx, const float* __restrict__ qz, const float* __restrict__ wu,
    const float* __restrict__ wv, const short* __restrict__ whi,
    const short* __restrict__ wlo, float* __restrict__ out, short* smem) {
  short* zhi = smem;                          // [96][136]
  short* zlo = smem + NP * TS_Z;              // [96][136]
  short* qhi = smem + 2 * NP * TS_Z;          // [96][72]
  short* qlo = qhi + NP * TS_Q;
  // phase2 aliases: zthi over DEAD zlo (so LDS->LDS transpose from zhi is
  // race-free); ahi over dead Q.
  short* zthi = smem + NP * TS_Z;             // [128][104] = 13312 shorts
  short* ahi  = smem + NP * TS_Z + ND * TS_T; // [96][104]  = 9984 shorts

  const int tid = threadIdx.x;
  const int l = tid & 63, w = tid >> 6;
  const int lm = l & 15, lk = l >> 4;
  const int c = idx & 127, b = idx >> 7;
  const float* zg = qz + ((size_t)(b * NC + c) * NP) * ND;

  // ---- stage z -> split bf16 ----
  for (int i = tid; i < NP * 32; i += 512) {
    int p = i >> 5, s = i & 31;
    float4 v = ((const float4*)zg)[i];
    uint2 r0 = split2(v.x, v.y), r1 = split2(v.z, v.w);
    *(uint2*)&zhi[p * TS_Z + 4 * s] = make_uint2(r0.x, r1.x);
    *(uint2*)&zlo[p * TS_Z + 4 * s] = make_uint2(r0.y, r1.y);
  }
  __syncthreads();

  const int nt = w & 3, mset = (w >> 2) * 3;
  const int vsel = nt & 1, hsel = nt >> 1;
  const float qsc = vsel ? 1.0f : 0.25f;

  float aacc[4][6] = {};
  const short8 z8 = {0, 0, 0, 0, 0, 0, 0, 0};
  const f32x4 zf = {0.f, 0.f, 0.f, 0.f};

  for (int hp = 0; hp < 4; ++hp) {
    const int hd = 2 * hp + hsel;
    u32x4 wbh[4], wbl[4];
    if constexpr (WS) {
      const size_t rb = (((size_t)vsel * 8 + b) * 128 + hd * NR + lm) * 128;
#pragma unroll
      for (int ks = 0; ks < 4; ++ks) {
        wbh[ks] = *(const u32x4*)&whi[rb + ks * 32 + lk * 8];
        wbl[ks] = *(const u32x4*)&wlo[rb + ks * 32 + lk * 8];
      }
    } else {
      const float* wrow = (vsel ? wv : wu) + ((size_t)b * ND + hd * NR + lm) * ND;
#pragma unroll
      for (int ks = 0; ks < 4; ++ks)
        split8(*(const float4*)(wrow + ks * 32 + lk * 8),
               *(const float4*)(wrow + ks * 32 + lk * 8 + 4), &wbh[ks], &wbl[ks]);
    }
    // ---- projection (full 3-term: accuracy anchor) ----
    f32x4 pacc[3] = {zf, zf, zf};
#pragma unroll
    for (int ks = 0; ks < 4; ++ks) {
#pragma unroll
      for (int mm = 0; mm < 3; ++mm) {
        int row = (mset + mm) * 16 + lm;
        short8 ah = *(const short8*)&zhi[row * TS_Z + ks * 32 + lk * 8];
        short8 al = *(const short8*)&zlo[row * TS_Z + ks * 32 + lk * 8];
        pacc[mm] = MFMA(ah, s8(wbh[ks]), pacc[mm]);
        pacc[mm] = MFMA(ah, s8(wbl[ks]), pacc[mm]);
        pacc[mm] = MFMA(al, s8(wbh[ks]), pacc[mm]);
      }
    }
#pragma unroll
    for (int mm = 0; mm < 3; ++mm) {
#pragma unroll
      for (int r = 0; r < 4; ++r) {
        float v = pacc[mm][r] * qsc;
        int row = (mset + mm) * 16 + lk * 4 + r, col = nt * 16 + lm;
        short hh = bfh(v);
        qhi[row * TS_Q + col] = hh;
        qlo[row * TS_Q + col] = bfh(v - bff(hh));
      }
    }
    __syncthreads();

    // ---- logits (2-term: hi*hi + hi*lo) + softmax (no max-sub); waves 0-5 ----
    if (w < 6) {
#pragma unroll
      for (int hh = 0; hh < 2; ++hh) {
        short8 ah = z8;
        if (l < 32)
          ah = *(const short8*)&qhi[(w * 16 + lm) * TS_Q + 32 * hh + lk * 8];
        f32x4 s[6];
#pragma unroll
        for (int qt = 0; qt < 6; ++qt) {
          s[qt] = zf;
          short8 bh = z8, bl = z8;
          if (l < 32) {
            bh = *(const short8*)&qhi[(qt * 16 + lm) * TS_Q + 32 * hh + 16 + lk * 8];
            bl = *(const short8*)&qlo[(qt * 16 + lm) * TS_Q + 32 * hh + 16 + lk * 8];
          }
          s[qt] = MFMA(ah, bh, s[qt]);
          s[qt] = MFMA(ah, bl, s[qt]);
        }
#pragma unroll
        for (int r = 0; r < 4; ++r) {
          float e[6], sum = 0.f;
#pragma unroll
          for (int qt = 0; qt < 6; ++qt) { e[qt] = __expf(s[qt][r]); sum += e[qt]; }
          sum += __shfl_xor(sum, 1);
          sum += __shfl_xor(sum, 2);
          sum += __shfl_xor(sum, 4);
          sum += __shfl_xor(sum, 8);
          float inv = 1.0f / sum;
#pragma unroll
          for (int qt = 0; qt < 6; ++qt) aacc[r][qt] += e[qt] * inv;
        }
      }
    }
    __syncthreads();
  }

  // ---- phase2: LDS->LDS transpose (zhi -> zthi over dead zlo) + abar ----
  for (int i = tid; i < NP * ND; i += 512) {
    int p = i >> 7, d = i & 127;
    zthi[d * TS_T + p] = zhi[p * TS_Z + d];
  }
  if (w < 6) {
#pragma unroll
    for (int r = 0; r < 4; ++r)
#pragma unroll
      for (int qt = 0; qt < 6; ++qt)
        ahi[(w * 16 + lk * 4 + r) * TS_T + qt * 16 + lm] = bfh(aacc[r][qt] * 0.125f);
  }
  __syncthreads();

  // ---- PV: m_t = abar @ z (zT-hi only; abar-hi only) ----
  float* og = out + ((size_t)(b * NC + c) * NP) * ND;
  f32x4 oacc[6] = {zf, zf, zf, zf, zf, zf};
#pragma unroll
  for (int ks = 0; ks < 3; ++ks) {
    short8 bh = *(const short8*)&zthi[(w * 16 + lm) * TS_T + ks * 32 + lk * 8];
#pragma unroll
    for (int m = 0; m < 6; ++m) {
      short8 a = *(const short8*)&ahi[(m * 16 + lm) * TS_T + ks * 32 + lk * 8];
      oacc[m] = MFMA(a, bh, oacc[m]);
    }
  }
#pragma unroll
  for (int m = 0; m < 6; ++m)
#pragma unroll
    for (int r = 0; r < 4; ++r)
      og[(m * 16 + lk * 4 + r) * ND + w * 16 + lm] = oacc[m][r];
}

// ================= channel-message body: idx -> (b, p) =================
template <int WS>
__device__ __forceinline__ void cmsg_body(
    int idx, const float* __restrict__ qz, const float* __restrict__ wu,
    const float* __restrict__ wv, const short* __restrict__ whi,
    const short* __restrict__ wlo, float* __restrict__ out, short* smem) {
  short* qhi_s = smem;                       // [128][72]
  short* qlo_s = smem + NC * TS_Q;
  short* wsthi = smem + 2 * NC * TS_Q;       // [4][16][136]
  short* wstlo = wsthi + 4 * 16 * TS_W;

  const int tid = threadIdx.x;
  const int l = tid & 63, w = tid >> 6;
  const int lm = l & 15, lk = l >> 4;
  const int p = idx % 96, b = idx / 96;

  // ---- z A-fragments for this wave's m-tile, split in regs ----
  u32x4 zah[4], zal[4];
  {
    const float* zrow = qz + ((size_t)(b * NC + w * 16 + lm) * NP + p) * ND;
#pragma unroll
    for (int ks = 0; ks < 4; ++ks)
      split8(*(const float4*)(zrow + ks * 32 + lk * 8),
             *(const float4*)(zrow + ks * 32 + lk * 8 + 4), &zah[ks], &zal[ks]);
  }

  float aacc[4][8] = {};
  const short8 z8 = {0, 0, 0, 0, 0, 0, 0, 0};
  const f32x4 zf = {0.f, 0.f, 0.f, 0.f};

  for (int hp = 0; hp < 4; ++hp) {
    // ---- cooperative W stage for all 4 nt of this hp ----
    if constexpr (WS) {
      for (int ci = tid; ci < 2048; ci += 512) {
        int buf = ci >> 10, ix = ci & 1023;
        int nt = ix >> 8, row = (ix >> 4) & 15, colc = ix & 15;
        int vs = nt & 1, hd = 2 * hp + (nt >> 1);
        const short* src = (buf ? wlo : whi) +
            (((size_t)(2 + vs) * 8 + b) * 128 + hd * NR + row) * 128 + colc * 8;
        short* dst = (buf ? wstlo : wsthi) + nt * (16 * TS_W) + row * TS_W + colc * 8;
        *(u32x4*)dst = *(const u32x4*)src;
      }
    } else {
      for (int ci = tid; ci < 1024; ci += 512) {
        int nt = ci >> 8, row = (ci >> 4) & 15, colc = ci & 15;
        int vs = nt & 1, hd = 2 * hp + (nt >> 1);
        const float* src = (vs ? wv : wu) + ((size_t)b * ND + hd * NR + row) * ND + colc * 8;
        u32x4 hi, lo;
        split8(*(const float4*)src, *(const float4*)(src + 4), &hi, &lo);
        *(u32x4*)&wsthi[nt * (16 * TS_W) + row * TS_W + colc * 8] = hi;
        *(u32x4*)&wstlo[nt * (16 * TS_W) + row * TS_W + colc * 8] = lo;
      }
    }
    __syncthreads();  // W ready; also fences prior logits' Q reads

    // ---- projection (full 3-term), W from LDS ----
#pragma unroll
    for (int nt = 0; nt < 4; ++nt) {
      f32x4 pacc = zf;
#pragma unroll
      for (int ks = 0; ks < 4; ++ks) {
        short8 bh = *(const short8*)&wsthi[nt * (16 * TS_W) + lm * TS_W + ks * 32 + lk * 8];
        short8 bl = *(const short8*)&wstlo[nt * (16 * TS_W) + lm * TS_W + ks * 32 + lk * 8];
        pacc = MFMA(s8(zah[ks]), bh, pacc);
        pacc = MFMA(s8(zah[ks]), bl, pacc);
        pacc = MFMA(s8(zal[ks]), bh, pacc);
      }
      const float qsc = (nt & 1) ? 1.0f : 0.25f;
#pragma unroll
      for (int r = 0; r < 4; ++r) {
        float v = pacc[r] * qsc;
        int row = w * 16 + lk * 4 + r, col = nt * 16 + lm;
        short hh = bfh(v);
        qhi_s[row * TS_Q + col] = hh;
        qlo_s[row * TS_Q + col] = bfh(v - bff(hh));
      }
    }
    __syncthreads();  // Q ready

    // ---- logits (2-term) + softmax over d' (no max-sub) ----
#pragma unroll
    for (int hh = 0; hh < 2; ++hh) {
      short8 ah = z8;
      if (l < 32)
        ah = *(const short8*)&qhi_s[(w * 16 + lm) * TS_Q + 32 * hh + lk * 8];
      f32x4 s[8];
#pragma unroll
      for (int qt = 0; qt < 8; ++qt) {
        s[qt] = zf;
        short8 bh = z8, bl = z8;
        if (l < 32) {
          bh = *(const short8*)&qhi_s[(qt * 16 + lm) * TS_Q + 32 * hh + 16 + lk * 8];
          bl = *(const short8*)&qlo_s[(qt * 16 + lm) * TS_Q + 32 * hh + 16 + lk * 8];
        }
        s[qt] = MFMA(ah, bh, s[qt]);
        s[qt] = MFMA(ah, bl, s[qt]);
      }
#pragma unroll
      for (int r = 0; r < 4; ++r) {
        float e[8], sum = 0.f;
#pragma unroll
        for (int qt = 0; qt < 8; ++qt) { e[qt] = __expf(s[qt][r]); sum += e[qt]; }
        sum += __shfl_xor(sum, 1);
        sum += __shfl_xor(sum, 2);
        sum += __shfl_xor(sum, 4);
        sum += __shfl_xor(sum, 8);
        float inv = 1.0f / sum;
#pragma unroll
        for (int qt = 0; qt < 8; ++qt) aacc[r][qt] += e[qt] * inv;
      }
    }
    // no barrier: next hp's W stage writes wst (disjoint from Q); its barrier
    // fences these Q reads before the next proj overwrites Q.
  }

  // ---- elementwise finish: m_c = (abar/8) * z, exact fp32 z from global ----
#pragma unroll
  for (int r = 0; r < 4; ++r) {
    int cc = w * 16 + lk * 4 + r;
    const float* zrow = qz + ((size_t)(b * NC + cc) * NP + p) * ND;
    float* orow = out + ((size_t)(b * NC + cc) * NP + p) * ND;
#pragma unroll
    for (int qt = 0; qt < 8; ++qt) {
      int d = qt * 16 + lm;
      orow[d] = 0.125f * aacc[r][qt] * zrow[d];
    }
  }
}

// ================= fused dispatcher =================
template <int WS>
__global__ __launch_bounds__(512, 2)
void fused_kernel(const float* __restrict__ qz, const float* __restrict__ tuw,
                  const float* __restrict__ tvw, const float* __restrict__ cuw,
                  const float* __restrict__ cvw, const short* __restrict__ whi,
                  const short* __restrict__ wlo, float* __restrict__ out_t,
                  float* __restrict__ out_c) {
  __shared__ __align__(16) short smem[39936];  // 79,872 B
  const int bid = blockIdx.x;
  const int r7 = bid % 7, q7 = bid / 7;
  if (r7 < 4)
    tmsg_body<WS>(q7 * 4 + r7, qz, tuw, tvw, whi, wlo, out_t, smem);
  else
    cmsg_body<WS>(q7 * 3 + (r7 - 4), qz, cuw, cvw, whi, wlo, out_c, smem);
}

extern "C" void kernel_launch(void* const* d_in, const int* in_sizes, int n_in,
                              void* d_out, int out_size, void* d_ws, size_t ws_size,
                              hipStream_t stream) {
  const float* qz  = (const float*)d_in[0];
  const float* tuw = (const float*)d_in[1];
  const float* tvw = (const float*)d_in[2];
  const float* cuw = (const float*)d_in[3];
  const float* cvw = (const float*)d_in[4];
  float* out_t = (float*)d_out;
  float* out_c = out_t + (size_t)NB * NC * NP * ND;

  if (ws_size >= W_NEED) {
    short* whi = (short*)d_ws;
    short* wlo = whi + W_ELEMS;
    prep_w<<<256, 256, 0, stream>>>(tuw, tvw, cuw, cvw, whi, wlo);
    fused_kernel<1><<<1792, 512, 0, stream>>>(qz, tuw, tvw, cuw, cvw, whi, wlo,
                                              out_t, out_c);
  } else {
    fused_kernel<0><<<1792, 512, 0, stream>>>(qz, tuw, tvw, cuw, cvw, nullptr,
                                              nullptr, out_t, out_c);
  }
}

// Round 15
// 171.741 us; speedup vs baseline: 1.5526x; 1.0739x over previous
//
#include <hip/hip_runtime.h>
#include <math.h>

#define NB 8
#define NC 128
#define NP 96
#define ND 128
#define NH 8
#define NR 16

typedef __attribute__((ext_vector_type(8))) short short8;
typedef __attribute__((ext_vector_type(4))) float f32x4;
typedef __attribute__((ext_vector_type(4))) unsigned u32x4;

#define MFMA(a, b, c) __builtin_amdgcn_mfma_f32_16x16x32_bf16((a), (b), (c), 0, 0, 0)

__device__ __forceinline__ short8 s8(u32x4 u) { return __builtin_bit_cast(short8, u); }

// scalar fp32 -> bf16 (RNE) and back
__device__ __forceinline__ unsigned bfh_u(float x) {
  unsigned u = __float_as_uint(x);
  unsigned r = u + 0x7fffu + ((u >> 16) & 1u);
  return r >> 16;
}
__device__ __forceinline__ short bfh(float x) { return (short)bfh_u(x); }
__device__ __forceinline__ float bff(short s) {
  return __uint_as_float(((unsigned)(unsigned short)s) << 16);
}

__device__ __forceinline__ uint2 split2(float a, float b) {
  unsigned ha = bfh_u(a), hb = bfh_u(b);
  float fa = __uint_as_float(ha << 16), fb = __uint_as_float(hb << 16);
  unsigned la = bfh_u(a - fa), lb = bfh_u(b - fb);
  return make_uint2(ha | (hb << 16), la | (lb << 16));
}

// hi-only pack of 2 floats
__device__ __forceinline__ unsigned hi2(float a, float b) {
  return bfh_u(a) | (bfh_u(b) << 16);
}

__device__ __forceinline__ void split8(const float4 x0, const float4 x1,
                                       u32x4* hi, u32x4* lo) {
  uint2 r0 = split2(x0.x, x0.y), r1 = split2(x0.z, x0.w);
  uint2 r2 = split2(x1.x, x1.y), r3 = split2(x1.z, x1.w);
  *hi = u32x4{r0.x, r1.x, r2.x, r3.x};
  *lo = u32x4{r0.y, r1.y, r2.y, r3.y};
}

// LDS row strides in shorts
#define TS_Z 136   // z-hi   [96][136]
#define TS_Q 72    // Q2     [rows][72]
#define TS_T 104   // zT/abar[rows][104]
#define TS_W 136   // W tile [16][136] per nt

#define W_ELEMS ((size_t)4 * 8 * 128 * 128)  // 524288 per split
#define W_NEED (W_ELEMS * 2 * 2)             // 2 MB

// ---------------- W split precompute: mats {tu, tv, cu, cv} ----------------
__global__ __launch_bounds__(256)
void prep_w(const float* __restrict__ w0, const float* __restrict__ w1,
            const float* __restrict__ w2, const float* __restrict__ w3,
            short* __restrict__ whi, short* __restrict__ wlo) {
  int t = blockIdx.x * 256 + threadIdx.x;
  int mat = t >> 14;
  size_t off = (size_t)(t & 16383) * 8;
  const float* srcs[4] = {w0, w1, w2, w3};
  const float* s = srcs[mat] + off;
  u32x4 hi, lo;
  split8(*(const float4*)s, *(const float4*)(s + 4), &hi, &lo);
  size_t base = (size_t)mat * 131072 + off;
  *(u32x4*)&whi[base] = hi;
  *(u32x4*)&wlo[base] = lo;
}

// ================= time-message body: idx -> (b, c) =================
// LDS phase1: zhi [96][136] @0 (13056) | qhi @13056 (6912) | qlo @19968 (6912)
// LDS phase2: zthi [128][104] @13056 (13312, over dead Q) | ahi [96][104] @0
//             (9984, over dead zhi, written AFTER transpose completes)
template <int WS>
__device__ __forceinline__ void tmsg_body(
    int idx, const float* __restrict__ qz, const float* __restrict__ wu,
    const float* __restrict__ wv, const short* __restrict__ whi,
    const short* __restrict__ wlo, float* __restrict__ out, short* smem) {
  short* zhi = smem;                    // [96][136]
  short* qhi = smem + NP * TS_Z;        // [96][72]
  short* qlo = qhi + NP * TS_Q;
  short* zthi = smem + NP * TS_Z;       // [128][104] (phase2, over dead Q)
  short* ahi  = smem;                   // [96][104]  (phase2, over dead zhi)

  const int tid = threadIdx.x;
  const int l = tid & 63, w = tid >> 6;
  const int lm = l & 15, lk = l >> 4;
  const int c = idx & 127, b = idx >> 7;
  const float* zg = qz + ((size_t)(b * NC + c) * NP) * ND;

  // ---- stage z -> bf16 hi only ----
  for (int i = tid; i < NP * 32; i += 512) {
    int p = i >> 5, s = i & 31;
    float4 v = ((const float4*)zg)[i];
    *(uint2*)&zhi[p * TS_Z + 4 * s] = make_uint2(hi2(v.x, v.y), hi2(v.z, v.w));
  }
  __syncthreads();

  const int nt = w & 3, mset = (w >> 2) * 3;
  const int vsel = nt & 1, hsel = nt >> 1;
  const float qsc = vsel ? 1.0f : 0.25f;

  float aacc[4][6] = {};
  const short8 z8 = {0, 0, 0, 0, 0, 0, 0, 0};
  const f32x4 zf = {0.f, 0.f, 0.f, 0.f};

  for (int hp = 0; hp < 4; ++hp) {
    const int hd = 2 * hp + hsel;
    u32x4 wbh[4], wbl[4];
    if constexpr (WS) {
      const size_t rb = (((size_t)vsel * 8 + b) * 128 + hd * NR + lm) * 128;
#pragma unroll
      for (int ks = 0; ks < 4; ++ks) {
        wbh[ks] = *(const u32x4*)&whi[rb + ks * 32 + lk * 8];
        wbl[ks] = *(const u32x4*)&wlo[rb + ks * 32 + lk * 8];
      }
    } else {
      const float* wrow = (vsel ? wv : wu) + ((size_t)b * ND + hd * NR + lm) * ND;
#pragma unroll
      for (int ks = 0; ks < 4; ++ks)
        split8(*(const float4*)(wrow + ks * 32 + lk * 8),
               *(const float4*)(wrow + ks * 32 + lk * 8 + 4), &wbh[ks], &wbl[ks]);
    }
    // ---- projection: 2-term, z-hi × (W-hi + W-lo) ----
    f32x4 pacc[3] = {zf, zf, zf};
#pragma unroll
    for (int ks = 0; ks < 4; ++ks) {
#pragma unroll
      for (int mm = 0; mm < 3; ++mm) {
        int row = (mset + mm) * 16 + lm;
        short8 ah = *(const short8*)&zhi[row * TS_Z + ks * 32 + lk * 8];
        pacc[mm] = MFMA(ah, s8(wbh[ks]), pacc[mm]);
        pacc[mm] = MFMA(ah, s8(wbl[ks]), pacc[mm]);
      }
    }
#pragma unroll
    for (int mm = 0; mm < 3; ++mm) {
#pragma unroll
      for (int r = 0; r < 4; ++r) {
        float v = pacc[mm][r] * qsc;
        int row = (mset + mm) * 16 + lk * 4 + r, col = nt * 16 + lm;
        short hh = bfh(v);
        qhi[row * TS_Q + col] = hh;
        qlo[row * TS_Q + col] = bfh(v - bff(hh));
      }
    }
    __syncthreads();

    // ---- logits (2-term: hi*hi + hi*lo) + softmax (no max-sub); waves 0-5 ----
    if (w < 6) {
#pragma unroll
      for (int hh = 0; hh < 2; ++hh) {
        short8 ah = z8;
        if (l < 32)
          ah = *(const short8*)&qhi[(w * 16 + lm) * TS_Q + 32 * hh + lk * 8];
        f32x4 s[6];
#pragma unroll
        for (int qt = 0; qt < 6; ++qt) {
          s[qt] = zf;
          short8 bh = z8, bl = z8;
          if (l < 32) {
            bh = *(const short8*)&qhi[(qt * 16 + lm) * TS_Q + 32 * hh + 16 + lk * 8];
            bl = *(const short8*)&qlo[(qt * 16 + lm) * TS_Q + 32 * hh + 16 + lk * 8];
          }
          s[qt] = MFMA(ah, bh, s[qt]);
          s[qt] = MFMA(ah, bl, s[qt]);
        }
#pragma unroll
        for (int r = 0; r < 4; ++r) {
          float e[6], sum = 0.f;
#pragma unroll
          for (int qt = 0; qt < 6; ++qt) { e[qt] = __expf(s[qt][r]); sum += e[qt]; }
          sum += __shfl_xor(sum, 1);
          sum += __shfl_xor(sum, 2);
          sum += __shfl_xor(sum, 4);
          sum += __shfl_xor(sum, 8);
          float inv = 1.0f / sum;
#pragma unroll
          for (int qt = 0; qt < 6; ++qt) aacc[r][qt] += e[qt] * inv;
        }
      }
    }
    __syncthreads();
  }

  // ---- phase2a: LDS->LDS transpose zhi -> zthi (over dead Q) ----
  for (int i = tid; i < NP * ND; i += 512) {
    int p = i >> 7, d = i & 127;
    zthi[d * TS_T + p] = zhi[p * TS_Z + d];
  }
  __syncthreads();  // zhi now dead
  // ---- phase2b: abar-hi over dead zhi ----
  if (w < 6) {
#pragma unroll
    for (int r = 0; r < 4; ++r)
#pragma unroll
      for (int qt = 0; qt < 6; ++qt)
        ahi[(w * 16 + lk * 4 + r) * TS_T + qt * 16 + lm] = bfh(aacc[r][qt] * 0.125f);
  }
  __syncthreads();

  // ---- PV: m_t = abar @ z (hi-only both sides) ----
  float* og = out + ((size_t)(b * NC + c) * NP) * ND;
  f32x4 oacc[6] = {zf, zf, zf, zf, zf, zf};
#pragma unroll
  for (int ks = 0; ks < 3; ++ks) {
    short8 bh = *(const short8*)&zthi[(w * 16 + lm) * TS_T + ks * 32 + lk * 8];
#pragma unroll
    for (int m = 0; m < 6; ++m) {
      short8 a = *(const short8*)&ahi[(m * 16 + lm) * TS_T + ks * 32 + lk * 8];
      oacc[m] = MFMA(a, bh, oacc[m]);
    }
  }
#pragma unroll
  for (int m = 0; m < 6; ++m)
#pragma unroll
    for (int r = 0; r < 4; ++r)
      og[(m * 16 + lk * 4 + r) * ND + w * 16 + lm] = oacc[m][r];
}

// ================= channel-message body: idx -> (b, p) =================
// LDS: qhi_s [128][72] @0 | qlo_s @9216 | wsthi [4][16][136] @18432  (27136 sh)
// z split in regs; proj 2-term: (z-hi + z-lo) × W-hi.
template <int WS>
__device__ __forceinline__ void cmsg_body(
    int idx, const float* __restrict__ qz, const float* __restrict__ wu,
    const float* __restrict__ wv, const short* __restrict__ whi,
    const short* __restrict__ wlo, float* __restrict__ out, short* smem) {
  short* qhi_s = smem;                       // [128][72]
  short* qlo_s = smem + NC * TS_Q;
  short* wsthi = smem + 2 * NC * TS_Q;       // [4][16][136]

  const int tid = threadIdx.x;
  const int l = tid & 63, w = tid >> 6;
  const int lm = l & 15, lk = l >> 4;
  const int p = idx % 96, b = idx / 96;

  // ---- z A-fragments for this wave's m-tile, split in regs ----
  u32x4 zah[4], zal[4];
  {
    const float* zrow = qz + ((size_t)(b * NC + w * 16 + lm) * NP + p) * ND;
#pragma unroll
    for (int ks = 0; ks < 4; ++ks)
      split8(*(const float4*)(zrow + ks * 32 + lk * 8),
             *(const float4*)(zrow + ks * 32 + lk * 8 + 4), &zah[ks], &zal[ks]);
  }

  float aacc[4][8] = {};
  const short8 z8 = {0, 0, 0, 0, 0, 0, 0, 0};
  const f32x4 zf = {0.f, 0.f, 0.f, 0.f};

  for (int hp = 0; hp < 4; ++hp) {
    // ---- cooperative W-hi stage for all 4 nt of this hp ----
    if constexpr (WS) {
      for (int ci = tid; ci < 1024; ci += 512) {
        int nt = ci >> 8, row = (ci >> 4) & 15, colc = ci & 15;
        int vs = nt & 1, hd = 2 * hp + (nt >> 1);
        const short* src = whi +
            (((size_t)(2 + vs) * 8 + b) * 128 + hd * NR + row) * 128 + colc * 8;
        *(u32x4*)&wsthi[nt * (16 * TS_W) + row * TS_W + colc * 8] = *(const u32x4*)src;
      }
    } else {
      for (int ci = tid; ci < 1024; ci += 512) {
        int nt = ci >> 8, row = (ci >> 4) & 15, colc = ci & 15;
        int vs = nt & 1, hd = 2 * hp + (nt >> 1);
        const float* src = (vs ? wv : wu) + ((size_t)b * ND + hd * NR + row) * ND + colc * 8;
        float4 x0 = *(const float4*)src, x1 = *(const float4*)(src + 4);
        *(u32x4*)&wsthi[nt * (16 * TS_W) + row * TS_W + colc * 8] =
            u32x4{hi2(x0.x, x0.y), hi2(x0.z, x0.w), hi2(x1.x, x1.y), hi2(x1.z, x1.w)};
      }
    }
    __syncthreads();  // W ready; also fences prior logits' Q reads

    // ---- projection: 2-term (z-hi + z-lo) × W-hi, W from LDS ----
#pragma unroll
    for (int nt = 0; nt < 4; ++nt) {
      f32x4 pacc = zf;
#pragma unroll
      for (int ks = 0; ks < 4; ++ks) {
        short8 bh = *(const short8*)&wsthi[nt * (16 * TS_W) + lm * TS_W + ks * 32 + lk * 8];
        pacc = MFMA(s8(zah[ks]), bh, pacc);
        pacc = MFMA(s8(zal[ks]), bh, pacc);
      }
      const float qsc = (nt & 1) ? 1.0f : 0.25f;
#pragma unroll
      for (int r = 0; r < 4; ++r) {
        float v = pacc[r] * qsc;
        int row = w * 16 + lk * 4 + r, col = nt * 16 + lm;
        short hh = bfh(v);
        qhi_s[row * TS_Q + col] = hh;
        qlo_s[row * TS_Q + col] = bfh(v - bff(hh));
      }
    }
    __syncthreads();  // Q ready

    // ---- logits (2-term) + softmax over d' (no max-sub) ----
#pragma unroll
    for (int hh = 0; hh < 2; ++hh) {
      short8 ah = z8;
      if (l < 32)
        ah = *(const short8*)&qhi_s[(w * 16 + lm) * TS_Q + 32 * hh + lk * 8];
      f32x4 s[8];
#pragma unroll
      for (int qt = 0; qt < 8; ++qt) {
        s[qt] = zf;
        short8 bh = z8, bl = z8;
        if (l < 32) {
          bh = *(const short8*)&qhi_s[(qt * 16 + lm) * TS_Q + 32 * hh + 16 + lk * 8];
          bl = *(const short8*)&qlo_s[(qt * 16 + lm) * TS_Q + 32 * hh + 16 + lk * 8];
        }
        s[qt] = MFMA(ah, bh, s[qt]);
        s[qt] = MFMA(ah, bl, s[qt]);
      }
#pragma unroll
      for (int r = 0; r < 4; ++r) {
        float e[8], sum = 0.f;
#pragma unroll
        for (int qt = 0; qt < 8; ++qt) { e[qt] = __expf(s[qt][r]); sum += e[qt]; }
        sum += __shfl_xor(sum, 1);
        sum += __shfl_xor(sum, 2);
        sum += __shfl_xor(sum, 4);
        sum += __shfl_xor(sum, 8);
        float inv = 1.0f / sum;
#pragma unroll
        for (int qt = 0; qt < 8; ++qt) aacc[r][qt] += e[qt] * inv;
      }
    }
    // no barrier: next hp's W stage barrier fences these Q reads.
  }

  // ---- elementwise finish: m_c = (abar/8) * z, exact fp32 z from global ----
#pragma unroll
  for (int r = 0; r < 4; ++r) {
    int cc = w * 16 + lk * 4 + r;
    const float* zrow = qz + ((size_t)(b * NC + cc) * NP + p) * ND;
    float* orow = out + ((size_t)(b * NC + cc) * NP + p) * ND;
#pragma unroll
    for (int qt = 0; qt < 8; ++qt) {
      int d = qt * 16 + lm;
      orow[d] = 0.125f * aacc[r][qt] * zrow[d];
    }
  }
}

// ================= fused dispatcher =================
// (512,3): VGPR cap 85, 3 blocks/CU at 54,272 B LDS -> 24 waves/CU.
template <int WS>
__global__ __launch_bounds__(512, 3)
void fused_kernel(const float* __restrict__ qz, const float* __restrict__ tuw,
                  const float* __restrict__ tvw, const float* __restrict__ cuw,
                  const float* __restrict__ cvw, const short* __restrict__ whi,
                  const short* __restrict__ wlo, float* __restrict__ out_t,
                  float* __restrict__ out_c) {
  __shared__ __align__(16) short smem[27136];  // 54,272 B
  const int bid = blockIdx.x;
  const int r7 = bid % 7, q7 = bid / 7;
  if (r7 < 4)
    tmsg_body<WS>(q7 * 4 + r7, qz, tuw, tvw, whi, wlo, out_t, smem);
  else
    cmsg_body<WS>(q7 * 3 + (r7 - 4), qz, cuw, cvw, whi, wlo, out_c, smem);
}

extern "C" void kernel_launch(void* const* d_in, const int* in_sizes, int n_in,
                              void* d_out, int out_size, void* d_ws, size_t ws_size,
                              hipStream_t stream) {
  const float* qz  = (const float*)d_in[0];
  const float* tuw = (const float*)d_in[1];
  const float* tvw = (const float*)d_in[2];
  const float* cuw = (const float*)d_in[3];
  const float* cvw = (const float*)d_in[4];
  float* out_t = (float*)d_out;
  float* out_c = out_t + (size_t)NB * NC * NP * ND;

  if (ws_size >= W_NEED) {
    short* whi = (short*)d_ws;
    short* wlo = whi + W_ELEMS;
    prep_w<<<256, 256, 0, stream>>>(tuw, tvw, cuw, cvw, whi, wlo);
    fused_kernel<1><<<1792, 512, 0, stream>>>(qz, tuw, tvw, cuw, cvw, whi, wlo,
                                              out_t, out_c);
  } else {
    fused_kernel<0><<<1792, 512, 0, stream>>>(qz, tuw, tvw, cuw, cvw, nullptr,
                                              nullptr, out_t, out_c);
  }
}

// Round 16
// 141.961 us; speedup vs baseline: 1.8783x; 1.2098x over previous
//
#include <hip/hip_runtime.h>
#include <math.h>

#define NB 8
#define NC 128
#define NP 96
#define ND 128
#define NH 8
#define NR 16

typedef __attribute__((ext_vector_type(8))) short short8;
typedef __attribute__((ext_vector_type(4))) float f32x4;
typedef __attribute__((ext_vector_type(4))) unsigned u32x4;

#define MFMA(a, b, c) __builtin_amdgcn_mfma_f32_16x16x32_bf16((a), (b), (c), 0, 0, 0)

__device__ __forceinline__ short8 s8(u32x4 u) { return __builtin_bit_cast(short8, u); }

// scalar fp32 -> bf16 (RNE) and back
__device__ __forceinline__ unsigned bfh_u(float x) {
  unsigned u = __float_as_uint(x);
  unsigned r = u + 0x7fffu + ((u >> 16) & 1u);
  return r >> 16;
}
__device__ __forceinline__ short bfh(float x) { return (short)bfh_u(x); }
__device__ __forceinline__ float bff(short s) {
  return __uint_as_float(((unsigned)(unsigned short)s) << 16);
}

__device__ __forceinline__ uint2 split2(float a, float b) {
  unsigned ha = bfh_u(a), hb = bfh_u(b);
  float fa = __uint_as_float(ha << 16), fb = __uint_as_float(hb << 16);
  unsigned la = bfh_u(a - fa), lb = bfh_u(b - fb);
  return make_uint2(ha | (hb << 16), la | (lb << 16));
}

// hi-only pack of 2 floats
__device__ __forceinline__ unsigned hi2(float a, float b) {
  return bfh_u(a) | (bfh_u(b) << 16);
}

__device__ __forceinline__ void split8(const float4 x0, const float4 x1,
                                       u32x4* hi, u32x4* lo) {
  uint2 r0 = split2(x0.x, x0.y), r1 = split2(x0.z, x0.w);
  uint2 r2 = split2(x1.x, x1.y), r3 = split2(x1.z, x1.w);
  *hi = u32x4{r0.x, r1.x, r2.x, r3.x};
  *lo = u32x4{r0.y, r1.y, r2.y, r3.y};
}

// LDS row strides in shorts
#define TS_Z 136   // z-hi   [96][136]
#define TS_Q 72    // Q-hi   [rows][72]
#define TS_T 104   // zT/abar[rows][104]
#define TS_W 136   // W tile [16][136] per nt

#define W_ELEMS ((size_t)4 * 8 * 128 * 128)  // 524288 per split
#define W_NEED (W_ELEMS * 2 * 2)             // 2 MB

// ---------------- W split precompute: mats {tu, tv, cu, cv} ----------------
__global__ __launch_bounds__(256)
void prep_w(const float* __restrict__ w0, const float* __restrict__ w1,
            const float* __restrict__ w2, const float* __restrict__ w3,
            short* __restrict__ whi, short* __restrict__ wlo) {
  int t = blockIdx.x * 256 + threadIdx.x;
  int mat = t >> 14;
  size_t off = (size_t)(t & 16383) * 8;
  const float* srcs[4] = {w0, w1, w2, w3};
  const float* s = srcs[mat] + off;
  u32x4 hi, lo;
  split8(*(const float4*)s, *(const float4*)(s + 4), &hi, &lo);
  size_t base = (size_t)mat * 131072 + off;
  *(u32x4*)&whi[base] = hi;
  *(u32x4*)&wlo[base] = lo;
}

// ================= time-message body: idx -> (b, c) =================
// LDS phase1: zhi [96][136] @0 (13056) | qA [96][72] @13056 | qB @19968
//   (Q double-buffered by hp parity -> ONE barrier per hp)
// LDS phase2: zthi [128][104] @13056 (over dead Q) | ahi [96][104] @0 (over
//   dead zhi, written after transpose completes)
template <int WS>
__device__ __forceinline__ void tmsg_body(
    int idx, const float* __restrict__ qz, const float* __restrict__ wu,
    const float* __restrict__ wv, const short* __restrict__ whi,
    const short* __restrict__ wlo, float* __restrict__ out, short* smem) {
  short* zhi = smem;                    // [96][136]
  short* qA  = smem + NP * TS_Z;        // [96][72]
  short* qB  = qA + NP * TS_Q;
  short* zthi = smem + NP * TS_Z;       // [128][104] (phase2)
  short* ahi  = smem;                   // [96][104]  (phase2)

  const int tid = threadIdx.x;
  const int l = tid & 63, w = tid >> 6;
  const int lm = l & 15, lk = l >> 4;
  const int c = idx & 127, b = idx >> 7;
  const float* zg = qz + ((size_t)(b * NC + c) * NP) * ND;

  // ---- stage z -> bf16 hi only ----
  for (int i = tid; i < NP * 32; i += 512) {
    int p = i >> 5, s = i & 31;
    float4 v = ((const float4*)zg)[i];
    *(uint2*)&zhi[p * TS_Z + 4 * s] = make_uint2(hi2(v.x, v.y), hi2(v.z, v.w));
  }
  __syncthreads();

  const int nt = w & 3, mset = (w >> 2) * 3;
  const int vsel = nt & 1, hsel = nt >> 1;
  const float qsc = vsel ? 1.0f : 0.25f;

  float aacc[4][6] = {};
  const short8 z8 = {0, 0, 0, 0, 0, 0, 0, 0};
  const f32x4 zf = {0.f, 0.f, 0.f, 0.f};

  short* qcur = qA;
  short* qnxt = qB;
  for (int hp = 0; hp < 4; ++hp) {
    const int hd = 2 * hp + hsel;
    u32x4 wbh[4], wbl[4];
    if constexpr (WS) {
      const size_t rb = (((size_t)vsel * 8 + b) * 128 + hd * NR + lm) * 128;
#pragma unroll
      for (int ks = 0; ks < 4; ++ks) {
        wbh[ks] = *(const u32x4*)&whi[rb + ks * 32 + lk * 8];
        wbl[ks] = *(const u32x4*)&wlo[rb + ks * 32 + lk * 8];
      }
    } else {
      const float* wrow = (vsel ? wv : wu) + ((size_t)b * ND + hd * NR + lm) * ND;
#pragma unroll
      for (int ks = 0; ks < 4; ++ks)
        split8(*(const float4*)(wrow + ks * 32 + lk * 8),
               *(const float4*)(wrow + ks * 32 + lk * 8 + 4), &wbh[ks], &wbl[ks]);
    }
    // ---- projection: 2-term, z-hi × (W-hi + W-lo); writes Q[parity] ----
    f32x4 pacc[3] = {zf, zf, zf};
#pragma unroll
    for (int ks = 0; ks < 4; ++ks) {
#pragma unroll
      for (int mm = 0; mm < 3; ++mm) {
        int row = (mset + mm) * 16 + lm;
        short8 ah = *(const short8*)&zhi[row * TS_Z + ks * 32 + lk * 8];
        pacc[mm] = MFMA(ah, s8(wbh[ks]), pacc[mm]);
        pacc[mm] = MFMA(ah, s8(wbl[ks]), pacc[mm]);
      }
    }
#pragma unroll
    for (int mm = 0; mm < 3; ++mm) {
#pragma unroll
      for (int r = 0; r < 4; ++r) {
        float v = pacc[mm][r] * qsc;
        int row = (mset + mm) * 16 + lk * 4 + r, col = nt * 16 + lm;
        qcur[row * TS_Q + col] = bfh(v);
      }
    }
    __syncthreads();  // Q[parity] ready

    // ---- logits (1-term hi*hi) + softmax (no max-sub); waves 0-5 ----
    // waves 6,7 skip and run ahead into next proj (writes qnxt: disjoint)
    if (w < 6) {
#pragma unroll
      for (int hh = 0; hh < 2; ++hh) {
        short8 ah = z8;
        if (l < 32)
          ah = *(const short8*)&qcur[(w * 16 + lm) * TS_Q + 32 * hh + lk * 8];
        f32x4 s[6];
#pragma unroll
        for (int qt = 0; qt < 6; ++qt) {
          s[qt] = zf;
          short8 bh = z8;
          if (l < 32)
            bh = *(const short8*)&qcur[(qt * 16 + lm) * TS_Q + 32 * hh + 16 + lk * 8];
          s[qt] = MFMA(ah, bh, s[qt]);
        }
#pragma unroll
        for (int r = 0; r < 4; ++r) {
          float e[6], sum = 0.f;
#pragma unroll
          for (int qt = 0; qt < 6; ++qt) { e[qt] = __expf(s[qt][r]); sum += e[qt]; }
          sum += __shfl_xor(sum, 1);
          sum += __shfl_xor(sum, 2);
          sum += __shfl_xor(sum, 4);
          sum += __shfl_xor(sum, 8);
          float inv = 1.0f / sum;
#pragma unroll
          for (int qt = 0; qt < 6; ++qt) aacc[r][qt] += e[qt] * inv;
        }
      }
    }
    short* t = qcur; qcur = qnxt; qnxt = t;  // no barrier: buffers disjoint
  }
  __syncthreads();  // all logits done before transpose overwrites Q region

  // ---- phase2a: LDS->LDS transpose zhi -> zthi (over dead Q) ----
  for (int i = tid; i < NP * ND; i += 512) {
    int p = i >> 7, d = i & 127;
    zthi[d * TS_T + p] = zhi[p * TS_Z + d];
  }
  __syncthreads();  // zhi now dead
  // ---- phase2b: abar-hi over dead zhi ----
  if (w < 6) {
#pragma unroll
    for (int r = 0; r < 4; ++r)
#pragma unroll
      for (int qt = 0; qt < 6; ++qt)
        ahi[(w * 16 + lk * 4 + r) * TS_T + qt * 16 + lm] = bfh(aacc[r][qt] * 0.125f);
  }
  __syncthreads();

  // ---- PV: m_t = abar @ z (hi-only both sides) ----
  float* og = out + ((size_t)(b * NC + c) * NP) * ND;
  f32x4 oacc[6] = {zf, zf, zf, zf, zf, zf};
#pragma unroll
  for (int ks = 0; ks < 3; ++ks) {
    short8 bh = *(const short8*)&zthi[(w * 16 + lm) * TS_T + ks * 32 + lk * 8];
#pragma unroll
    for (int m = 0; m < 6; ++m) {
      short8 a = *(const short8*)&ahi[(m * 16 + lm) * TS_T + ks * 32 + lk * 8];
      oacc[m] = MFMA(a, bh, oacc[m]);
    }
  }
#pragma unroll
  for (int m = 0; m < 6; ++m)
#pragma unroll
    for (int r = 0; r < 4; ++r)
      og[(m * 16 + lk * 4 + r) * ND + w * 16 + lm] = oacc[m][r];
}

// ================= channel-message body: idx -> (b, p) =================
// LDS: qhi_s [128][72] @0 (9216) | wstA [4][16][136] @9216 | wstB @17920
// z split in regs; proj 2-term (z-hi + z-lo) × W-hi; W double-buffered with
// register prefetch (issue loads before proj, LDS-write after: T14 pattern).
template <int WS>
__device__ __forceinline__ void cmsg_body(
    int idx, const float* __restrict__ qz, const float* __restrict__ wu,
    const float* __restrict__ wv, const short* __restrict__ whi,
    const short* __restrict__ wlo, float* __restrict__ out, short* smem) {
  short* qhi_s = smem;                       // [128][72]
  short* wstA = smem + NC * TS_Q;            // [4][16][136]
  short* wstB = wstA + 4 * 16 * TS_W;

  const int tid = threadIdx.x;
  const int l = tid & 63, w = tid >> 6;
  const int lm = l & 15, lk = l >> 4;
  const int p = idx % 96, b = idx / 96;

  // chunk decode for cooperative W staging: ci in [0,1024)
  const int ci0 = tid, ci1 = tid + 512;
  const int nt0 = ci0 >> 8, row0 = (ci0 >> 4) & 15, colc0 = ci0 & 15;
  const int nt1 = ci1 >> 8, row1 = (ci1 >> 4) & 15, colc1 = ci1 & 15;
  const int vs0 = nt0 & 1, vs1 = nt1 & 1;

  // ---- stage W[0] directly into wstA ----
  {
    const int hd0 = vs0 ? 0 : 0;  // hp=0: hd = nt>>1
#pragma unroll
    for (int cc = 0; cc < 2; ++cc) {
      int nt = cc ? nt1 : nt0, row = cc ? row1 : row0, colc = cc ? colc1 : colc0;
      int vs = nt & 1, hd = (nt >> 1);
      if constexpr (WS) {
        const short* src = whi +
            (((size_t)(2 + vs) * 8 + b) * 128 + hd * NR + row) * 128 + colc * 8;
        *(u32x4*)&wstA[nt * (16 * TS_W) + row * TS_W + colc * 8] = *(const u32x4*)src;
      } else {
        const float* src = (vs ? wv : wu) + ((size_t)b * ND + hd * NR + row) * ND + colc * 8;
        float4 x0 = *(const float4*)src, x1 = *(const float4*)(src + 4);
        *(u32x4*)&wstA[nt * (16 * TS_W) + row * TS_W + colc * 8] =
            u32x4{hi2(x0.x, x0.y), hi2(x0.z, x0.w), hi2(x1.x, x1.y), hi2(x1.z, x1.w)};
      }
    }
    (void)hd0;
  }

  // ---- z A-fragments for this wave's m-tile, split in regs ----
  u32x4 zah[4], zal[4];
  {
    const float* zrow = qz + ((size_t)(b * NC + w * 16 + lm) * NP + p) * ND;
#pragma unroll
    for (int ks = 0; ks < 4; ++ks)
      split8(*(const float4*)(zrow + ks * 32 + lk * 8),
             *(const float4*)(zrow + ks * 32 + lk * 8 + 4), &zah[ks], &zal[ks]);
  }
  __syncthreads();  // W[0] ready

  float aacc[4][8] = {};
  const short8 z8 = {0, 0, 0, 0, 0, 0, 0, 0};
  const f32x4 zf = {0.f, 0.f, 0.f, 0.f};

  short* wcur = wstA;
  short* wnxt = wstB;
  for (int hp = 0; hp < 4; ++hp) {
    // ---- issue W[hp+1] prefetch loads (latency hides under proj) ----
    u32x4 pf0 = {}, pf1 = {};
    float4 f00 = {}, f01 = {}, f10 = {}, f11 = {};
    const bool havepf = hp < 3;
    if (havepf) {
      const int hd0 = 2 * (hp + 1) + (nt0 >> 1), hd1 = 2 * (hp + 1) + (nt1 >> 1);
      if constexpr (WS) {
        pf0 = *(const u32x4*)(whi +
            (((size_t)(2 + vs0) * 8 + b) * 128 + hd0 * NR + row0) * 128 + colc0 * 8);
        pf1 = *(const u32x4*)(whi +
            (((size_t)(2 + vs1) * 8 + b) * 128 + hd1 * NR + row1) * 128 + colc1 * 8);
      } else {
        const float* s0 = (vs0 ? wv : wu) + ((size_t)b * ND + hd0 * NR + row0) * ND + colc0 * 8;
        const float* s1 = (vs1 ? wv : wu) + ((size_t)b * ND + hd1 * NR + row1) * ND + colc1 * 8;
        f00 = *(const float4*)s0; f01 = *(const float4*)(s0 + 4);
        f10 = *(const float4*)s1; f11 = *(const float4*)(s1 + 4);
      }
    }

    // ---- projection: 2-term (z-hi + z-lo) × W-hi from wcur ----
#pragma unroll
    for (int nt = 0; nt < 4; ++nt) {
      f32x4 pacc = zf;
#pragma unroll
      for (int ks = 0; ks < 4; ++ks) {
        short8 bh = *(const short8*)&wcur[nt * (16 * TS_W) + lm * TS_W + ks * 32 + lk * 8];
        pacc = MFMA(s8(zah[ks]), bh, pacc);
        pacc = MFMA(s8(zal[ks]), bh, pacc);
      }
      const float qsc = (nt & 1) ? 1.0f : 0.25f;
#pragma unroll
      for (int r = 0; r < 4; ++r) {
        float v = pacc[r] * qsc;
        qhi_s[(w * 16 + lk * 4 + r) * TS_Q + nt * 16 + lm] = bfh(v);
      }
    }
    // ---- write prefetched W[hp+1] into wnxt ----
    if (havepf) {
      if constexpr (WS) {
        *(u32x4*)&wnxt[nt0 * (16 * TS_W) + row0 * TS_W + colc0 * 8] = pf0;
        *(u32x4*)&wnxt[nt1 * (16 * TS_W) + row1 * TS_W + colc1 * 8] = pf1;
      } else {
        *(u32x4*)&wnxt[nt0 * (16 * TS_W) + row0 * TS_W + colc0 * 8] =
            u32x4{hi2(f00.x, f00.y), hi2(f00.z, f00.w), hi2(f01.x, f01.y), hi2(f01.z, f01.w)};
        *(u32x4*)&wnxt[nt1 * (16 * TS_W) + row1 * TS_W + colc1 * 8] =
            u32x4{hi2(f10.x, f10.y), hi2(f10.z, f10.w), hi2(f11.x, f11.y), hi2(f11.z, f11.w)};
      }
    }
    __syncthreads();  // Q ready + W[hp+1] committed

    // ---- logits (1-term hi*hi) + softmax over d' (no max-sub) ----
#pragma unroll
    for (int hh = 0; hh < 2; ++hh) {
      short8 ah = z8;
      if (l < 32)
        ah = *(const short8*)&qhi_s[(w * 16 + lm) * TS_Q + 32 * hh + lk * 8];
      f32x4 s[8];
#pragma unroll
      for (int qt = 0; qt < 8; ++qt) {
        s[qt] = zf;
        short8 bh = z8;
        if (l < 32)
          bh = *(const short8*)&qhi_s[(qt * 16 + lm) * TS_Q + 32 * hh + 16 + lk * 8];
        s[qt] = MFMA(ah, bh, s[qt]);
      }
#pragma unroll
      for (int r = 0; r < 4; ++r) {
        float e[8], sum = 0.f;
#pragma unroll
        for (int qt = 0; qt < 8; ++qt) { e[qt] = __expf(s[qt][r]); sum += e[qt]; }
        sum += __shfl_xor(sum, 1);
        sum += __shfl_xor(sum, 2);
        sum += __shfl_xor(sum, 4);
        sum += __shfl_xor(sum, 8);
        float inv = 1.0f / sum;
#pragma unroll
        for (int qt = 0; qt < 8; ++qt) aacc[r][qt] += e[qt] * inv;
      }
    }
    __syncthreads();  // Q reads done before next proj overwrites qhi_s
    short* t = wcur; wcur = wnxt; wnxt = t;
  }

  // ---- elementwise finish: m_c = (abar/8) * z, exact fp32 z from global ----
#pragma unroll
  for (int r = 0; r < 4; ++r) {
    int cc = w * 16 + lk * 4 + r;
    const float* zrow = qz + ((size_t)(b * NC + cc) * NP + p) * ND;
    float* orow = out + ((size_t)(b * NC + cc) * NP + p) * ND;
#pragma unroll
    for (int qt = 0; qt < 8; ++qt) {
      int d = qt * 16 + lm;
      orow[d] = 0.125f * aacc[r][qt] * zrow[d];
    }
  }
}

// ================= fused dispatcher =================
// (512,3): VGPR cap 85 (verified R15: reports 84); LDS 53,760 -> 3 blocks/CU.
template <int WS>
__global__ __launch_bounds__(512, 3)
void fused_kernel(const float* __restrict__ qz, const float* __restrict__ tuw,
                  const float* __restrict__ tvw, const float* __restrict__ cuw,
                  const float* __restrict__ cvw, const short* __restrict__ whi,
                  const short* __restrict__ wlo, float* __restrict__ out_t,
                  float* __restrict__ out_c) {
  __shared__ __align__(16) short smem[26880];  // 53,760 B
  const int bid = blockIdx.x;
  const int r7 = bid % 7, q7 = bid / 7;
  if (r7 < 4)
    tmsg_body<WS>(q7 * 4 + r7, qz, tuw, tvw, whi, wlo, out_t, smem);
  else
    cmsg_body<WS>(q7 * 3 + (r7 - 4), qz, cuw, cvw, whi, wlo, out_c, smem);
}

extern "C" void kernel_launch(void* const* d_in, const int* in_sizes, int n_in,
                              void* d_out, int out_size, void* d_ws, size_t ws_size,
                              hipStream_t stream) {
  const float* qz  = (const float*)d_in[0];
  const float* tuw = (const float*)d_in[1];
  const float* tvw = (const float*)d_in[2];
  const float* cuw = (const float*)d_in[3];
  const float* cvw = (const float*)d_in[4];
  float* out_t = (float*)d_out;
  float* out_c = out_t + (size_t)NB * NC * NP * ND;

  if (ws_size >= W_NEED) {
    short* whi = (short*)d_ws;
    short* wlo = whi + W_ELEMS;
    prep_w<<<256, 256, 0, stream>>>(tuw, tvw, cuw, cvw, whi, wlo);
    fused_kernel<1><<<1792, 512, 0, stream>>>(qz, tuw, tvw, cuw, cvw, whi, wlo,
                                              out_t, out_c);
  } else {
    fused_kernel<0><<<1792, 512, 0, stream>>>(qz, tuw, tvw, cuw, cvw, nullptr,
                                              nullptr, out_t, out_c);
  }
}

// Round 17
// 138.675 us; speedup vs baseline: 1.9228x; 1.0237x over previous
//
#include <hip/hip_runtime.h>
#include <math.h>

#define NB 8
#define NC 128
#define NP 96
#define ND 128
#define NH 8
#define NR 16

typedef __attribute__((ext_vector_type(8))) short short8;
typedef __attribute__((ext_vector_type(4))) float f32x4;
typedef __attribute__((ext_vector_type(4))) unsigned u32x4;

#define MFMA(a, b, c) __builtin_amdgcn_mfma_f32_16x16x32_bf16((a), (b), (c), 0, 0, 0)

// log2(e): folded into the Qu projection scale so softmax uses exp2 directly
#define QU_SCALE (0.25f * 1.44269504f)

__device__ __forceinline__ short8 s8(u32x4 u) { return __builtin_bit_cast(short8, u); }

// scalar fp32 -> bf16 (RNE) and back
__device__ __forceinline__ unsigned bfh_u(float x) {
  unsigned u = __float_as_uint(x);
  unsigned r = u + 0x7fffu + ((u >> 16) & 1u);
  return r >> 16;
}
__device__ __forceinline__ short bfh(float x) { return (short)bfh_u(x); }

__device__ __forceinline__ uint2 split2(float a, float b) {
  unsigned ha = bfh_u(a), hb = bfh_u(b);
  float fa = __uint_as_float(ha << 16), fb = __uint_as_float(hb << 16);
  unsigned la = bfh_u(a - fa), lb = bfh_u(b - fb);
  return make_uint2(ha | (hb << 16), la | (lb << 16));
}

// hi-only pack of 2 floats
__device__ __forceinline__ unsigned hi2(float a, float b) {
  return bfh_u(a) | (bfh_u(b) << 16);
}

__device__ __forceinline__ void split8(const float4 x0, const float4 x1,
                                       u32x4* hi, u32x4* lo) {
  uint2 r0 = split2(x0.x, x0.y), r1 = split2(x0.z, x0.w);
  uint2 r2 = split2(x1.x, x1.y), r3 = split2(x1.z, x1.w);
  *hi = u32x4{r0.x, r1.x, r2.x, r3.x};
  *lo = u32x4{r0.y, r1.y, r2.y, r3.y};
}

// LDS row strides in shorts
#define TS_Z 136   // z-hi   [96][136]
#define TS_Q 72    // Q-hi   [rows][72]
#define TS_T 104   // zT/abar[rows][104]
#define TS_W 136   // W tile [16][136] per nt

#define W_ELEMS ((size_t)4 * 8 * 128 * 128)  // 524288 per split
#define W_NEED (W_ELEMS * 2 * 2)             // 2 MB (layout kept; only hi used)

// ---------------- W-hi precompute: mats {tu, tv, cu, cv} ----------------
__global__ __launch_bounds__(256)
void prep_w(const float* __restrict__ w0, const float* __restrict__ w1,
            const float* __restrict__ w2, const float* __restrict__ w3,
            short* __restrict__ whi, short* __restrict__ wlo) {
  int t = blockIdx.x * 256 + threadIdx.x;
  int mat = t >> 14;
  size_t off = (size_t)(t & 16383) * 8;
  const float* srcs[4] = {w0, w1, w2, w3};
  const float* s = srcs[mat] + off;
  float4 x0 = *(const float4*)s, x1 = *(const float4*)(s + 4);
  size_t base = (size_t)mat * 131072 + off;
  *(u32x4*)&whi[base] =
      u32x4{hi2(x0.x, x0.y), hi2(x0.z, x0.w), hi2(x1.x, x1.y), hi2(x1.z, x1.w)};
  (void)wlo;
}

// ================= time-message body: idx -> (b, c) =================
// LDS phase1: zhi [96][136] @0 (13056) | qA [96][72] @13056 | qB @19968
// LDS phase2: zthi [128][104] @13056 (over dead Q) | ahi [96][104] @0
template <int WS>
__device__ __forceinline__ void tmsg_body(
    int idx, const float* __restrict__ qz, const float* __restrict__ wu,
    const float* __restrict__ wv, const short* __restrict__ whi,
    const short* __restrict__ wlo, float* __restrict__ out, short* smem) {
  short* zhi = smem;                    // [96][136]
  short* qA  = smem + NP * TS_Z;        // [96][72]
  short* qB  = qA + NP * TS_Q;
  short* zthi = smem + NP * TS_Z;       // [128][104] (phase2)
  short* ahi  = smem;                   // [96][104]  (phase2)

  const int tid = threadIdx.x;
  const int l = tid & 63, w = tid >> 6;
  const int lm = l & 15, lk = l >> 4;
  const int c = idx & 127, b = idx >> 7;
  const float* zg = qz + ((size_t)(b * NC + c) * NP) * ND;

  // ---- stage z -> bf16 hi only ----
  for (int i = tid; i < NP * 32; i += 512) {
    int p = i >> 5, s = i & 31;
    float4 v = ((const float4*)zg)[i];
    *(uint2*)&zhi[p * TS_Z + 4 * s] = make_uint2(hi2(v.x, v.y), hi2(v.z, v.w));
  }
  __syncthreads();

  const int nt = w & 3, mset = (w >> 2) * 3;
  const int vsel = nt & 1, hsel = nt >> 1;
  const float qsc = vsel ? 1.0f : QU_SCALE;

  float aacc[4][6] = {};
  const short8 z8 = {0, 0, 0, 0, 0, 0, 0, 0};
  const f32x4 zf = {0.f, 0.f, 0.f, 0.f};

  short* qcur = qA;
  short* qnxt = qB;
  for (int hp = 0; hp < 4; ++hp) {
    const int hd = 2 * hp + hsel;
    // ---- W-hi fragments for this wave's nt ----
    u32x4 wbh[4];
    if constexpr (WS) {
      const size_t rb = (((size_t)vsel * 8 + b) * 128 + hd * NR + lm) * 128;
#pragma unroll
      for (int ks = 0; ks < 4; ++ks)
        wbh[ks] = *(const u32x4*)&whi[rb + ks * 32 + lk * 8];
    } else {
      const float* wrow = (vsel ? wv : wu) + ((size_t)b * ND + hd * NR + lm) * ND;
#pragma unroll
      for (int ks = 0; ks < 4; ++ks) {
        float4 x0 = *(const float4*)(wrow + ks * 32 + lk * 8);
        float4 x1 = *(const float4*)(wrow + ks * 32 + lk * 8 + 4);
        wbh[ks] = u32x4{hi2(x0.x, x0.y), hi2(x0.z, x0.w),
                        hi2(x1.x, x1.y), hi2(x1.z, x1.w)};
      }
    }
    // ---- projection: pure bf16, z-hi × W-hi; writes Q[parity] ----
    f32x4 pacc[3] = {zf, zf, zf};
#pragma unroll
    for (int ks = 0; ks < 4; ++ks) {
#pragma unroll
      for (int mm = 0; mm < 3; ++mm) {
        int row = (mset + mm) * 16 + lm;
        short8 ah = *(const short8*)&zhi[row * TS_Z + ks * 32 + lk * 8];
        pacc[mm] = MFMA(ah, s8(wbh[ks]), pacc[mm]);
      }
    }
#pragma unroll
    for (int mm = 0; mm < 3; ++mm) {
#pragma unroll
      for (int r = 0; r < 4; ++r) {
        float v = pacc[mm][r] * qsc;
        int row = (mset + mm) * 16 + lk * 4 + r, col = nt * 16 + lm;
        qcur[row * TS_Q + col] = bfh(v);
      }
    }
    __syncthreads();  // Q[parity] ready

    // ---- logits (1-term) + softmax (exp2, fast rcp); waves 0-5 ----
    if (w < 6) {
#pragma unroll
      for (int hh = 0; hh < 2; ++hh) {
        short8 ah = z8;
        if (l < 32)
          ah = *(const short8*)&qcur[(w * 16 + lm) * TS_Q + 32 * hh + lk * 8];
        f32x4 s[6];
#pragma unroll
        for (int qt = 0; qt < 6; ++qt) {
          s[qt] = zf;
          short8 bh = z8;
          if (l < 32)
            bh = *(const short8*)&qcur[(qt * 16 + lm) * TS_Q + 32 * hh + 16 + lk * 8];
          s[qt] = MFMA(ah, bh, s[qt]);
        }
#pragma unroll
        for (int r = 0; r < 4; ++r) {
          float e[6], sum = 0.f;
#pragma unroll
          for (int qt = 0; qt < 6; ++qt) { e[qt] = exp2f(s[qt][r]); sum += e[qt]; }
          sum += __shfl_xor(sum, 1);
          sum += __shfl_xor(sum, 2);
          sum += __shfl_xor(sum, 4);
          sum += __shfl_xor(sum, 8);
          float inv = __builtin_amdgcn_rcpf(sum);
#pragma unroll
          for (int qt = 0; qt < 6; ++qt) aacc[r][qt] += e[qt] * inv;
        }
      }
    }
    short* t = qcur; qcur = qnxt; qnxt = t;  // buffers disjoint: no barrier
  }
  __syncthreads();  // all logits done before transpose overwrites Q region

  // ---- phase2a: LDS->LDS transpose zhi -> zthi (over dead Q) ----
  for (int i = tid; i < NP * ND; i += 512) {
    int p = i >> 7, d = i & 127;
    zthi[d * TS_T + p] = zhi[p * TS_Z + d];
  }
  __syncthreads();  // zhi now dead
  // ---- phase2b: abar-hi over dead zhi ----
  if (w < 6) {
#pragma unroll
    for (int r = 0; r < 4; ++r)
#pragma unroll
      for (int qt = 0; qt < 6; ++qt)
        ahi[(w * 16 + lk * 4 + r) * TS_T + qt * 16 + lm] = bfh(aacc[r][qt] * 0.125f);
  }
  __syncthreads();

  // ---- PV: m_t = abar @ z (hi-only both sides) ----
  float* og = out + ((size_t)(b * NC + c) * NP) * ND;
  f32x4 oacc[6] = {zf, zf, zf, zf, zf, zf};
#pragma unroll
  for (int ks = 0; ks < 3; ++ks) {
    short8 bh = *(const short8*)&zthi[(w * 16 + lm) * TS_T + ks * 32 + lk * 8];
#pragma unroll
    for (int m = 0; m < 6; ++m) {
      short8 a = *(const short8*)&ahi[(m * 16 + lm) * TS_T + ks * 32 + lk * 8];
      oacc[m] = MFMA(a, bh, oacc[m]);
    }
  }
#pragma unroll
  for (int m = 0; m < 6; ++m)
#pragma unroll
    for (int r = 0; r < 4; ++r)
      og[(m * 16 + lk * 4 + r) * ND + w * 16 + lm] = oacc[m][r];
}

// ================= channel-message body: idx -> (b, p) =================
// LDS: qhi_s [128][72] @0 (9216) | wstA [4][16][136] @9216 | wstB @17920
// z-hi in regs (pure bf16); W-hi double-buffered with register prefetch.
template <int WS>
__device__ __forceinline__ void cmsg_body(
    int idx, const float* __restrict__ qz, const float* __restrict__ wu,
    const float* __restrict__ wv, const short* __restrict__ whi,
    const short* __restrict__ wlo, float* __restrict__ out, short* smem) {
  short* qhi_s = smem;                       // [128][72]
  short* wstA = smem + NC * TS_Q;            // [4][16][136]
  short* wstB = wstA + 4 * 16 * TS_W;

  const int tid = threadIdx.x;
  const int l = tid & 63, w = tid >> 6;
  const int lm = l & 15, lk = l >> 4;
  const int p = idx % 96, b = idx / 96;

  // chunk decode for cooperative W staging: ci in [0,1024)
  const int ci0 = tid, ci1 = tid + 512;
  const int nt0 = ci0 >> 8, row0 = (ci0 >> 4) & 15, colc0 = ci0 & 15;
  const int nt1 = ci1 >> 8, row1 = (ci1 >> 4) & 15, colc1 = ci1 & 15;
  const int vs0 = nt0 & 1, vs1 = nt1 & 1;

  // ---- stage W[0] directly into wstA ----
  {
#pragma unroll
    for (int cc = 0; cc < 2; ++cc) {
      int nt = cc ? nt1 : nt0, row = cc ? row1 : row0, colc = cc ? colc1 : colc0;
      int vs = nt & 1, hd = (nt >> 1);
      if constexpr (WS) {
        const short* src = whi +
            (((size_t)(2 + vs) * 8 + b) * 128 + hd * NR + row) * 128 + colc * 8;
        *(u32x4*)&wstA[nt * (16 * TS_W) + row * TS_W + colc * 8] = *(const u32x4*)src;
      } else {
        const float* src = (vs ? wv : wu) + ((size_t)b * ND + hd * NR + row) * ND + colc * 8;
        float4 x0 = *(const float4*)src, x1 = *(const float4*)(src + 4);
        *(u32x4*)&wstA[nt * (16 * TS_W) + row * TS_W + colc * 8] =
            u32x4{hi2(x0.x, x0.y), hi2(x0.z, x0.w), hi2(x1.x, x1.y), hi2(x1.z, x1.w)};
      }
    }
  }

  // ---- z-hi A-fragments for this wave's m-tile (pure bf16) ----
  u32x4 zah[4];
  {
    const float* zrow = qz + ((size_t)(b * NC + w * 16 + lm) * NP + p) * ND;
#pragma unroll
    for (int ks = 0; ks < 4; ++ks) {
      float4 x0 = *(const float4*)(zrow + ks * 32 + lk * 8);
      float4 x1 = *(const float4*)(zrow + ks * 32 + lk * 8 + 4);
      zah[ks] = u32x4{hi2(x0.x, x0.y), hi2(x0.z, x0.w),
                      hi2(x1.x, x1.y), hi2(x1.z, x1.w)};
    }
  }
  __syncthreads();  // W[0] ready

  float aacc[4][8] = {};
  const short8 z8 = {0, 0, 0, 0, 0, 0, 0, 0};
  const f32x4 zf = {0.f, 0.f, 0.f, 0.f};

  short* wcur = wstA;
  short* wnxt = wstB;
  for (int hp = 0; hp < 4; ++hp) {
    // ---- issue W[hp+1] prefetch loads (latency hides under proj) ----
    u32x4 pf0 = {}, pf1 = {};
    float4 f00 = {}, f01 = {}, f10 = {}, f11 = {};
    const bool havepf = hp < 3;
    if (havepf) {
      const int hd0 = 2 * (hp + 1) + (nt0 >> 1), hd1 = 2 * (hp + 1) + (nt1 >> 1);
      if constexpr (WS) {
        pf0 = *(const u32x4*)(whi +
            (((size_t)(2 + vs0) * 8 + b) * 128 + hd0 * NR + row0) * 128 + colc0 * 8);
        pf1 = *(const u32x4*)(whi +
            (((size_t)(2 + vs1) * 8 + b) * 128 + hd1 * NR + row1) * 128 + colc1 * 8);
      } else {
        const float* s0 = (vs0 ? wv : wu) + ((size_t)b * ND + hd0 * NR + row0) * ND + colc0 * 8;
        const float* s1 = (vs1 ? wv : wu) + ((size_t)b * ND + hd1 * NR + row1) * ND + colc1 * 8;
        f00 = *(const float4*)s0; f01 = *(const float4*)(s0 + 4);
        f10 = *(const float4*)s1; f11 = *(const float4*)(s1 + 4);
      }
    }

    // ---- projection: pure bf16, z-hi × W-hi from wcur ----
#pragma unroll
    for (int nt = 0; nt < 4; ++nt) {
      f32x4 pacc = zf;
#pragma unroll
      for (int ks = 0; ks < 4; ++ks) {
        short8 bh = *(const short8*)&wcur[nt * (16 * TS_W) + lm * TS_W + ks * 32 + lk * 8];
        pacc = MFMA(s8(zah[ks]), bh, pacc);
      }
      const float qsc = (nt & 1) ? 1.0f : QU_SCALE;
#pragma unroll
      for (int r = 0; r < 4; ++r) {
        float v = pacc[r] * qsc;
        qhi_s[(w * 16 + lk * 4 + r) * TS_Q + nt * 16 + lm] = bfh(v);
      }
    }
    // ---- write prefetched W[hp+1] into wnxt ----
    if (havepf) {
      if constexpr (WS) {
        *(u32x4*)&wnxt[nt0 * (16 * TS_W) + row0 * TS_W + colc0 * 8] = pf0;
        *(u32x4*)&wnxt[nt1 * (16 * TS_W) + row1 * TS_W + colc1 * 8] = pf1;
      } else {
        *(u32x4*)&wnxt[nt0 * (16 * TS_W) + row0 * TS_W + colc0 * 8] =
            u32x4{hi2(f00.x, f00.y), hi2(f00.z, f00.w), hi2(f01.x, f01.y), hi2(f01.z, f01.w)};
        *(u32x4*)&wnxt[nt1 * (16 * TS_W) + row1 * TS_W + colc1 * 8] =
            u32x4{hi2(f10.x, f10.y), hi2(f10.z, f10.w), hi2(f11.x, f11.y), hi2(f11.z, f11.w)};
      }
    }
    __syncthreads();  // Q ready + W[hp+1] committed

    // ---- logits (1-term) + softmax over d' (exp2, fast rcp) ----
#pragma unroll
    for (int hh = 0; hh < 2; ++hh) {
      short8 ah = z8;
      if (l < 32)
        ah = *(const short8*)&qhi_s[(w * 16 + lm) * TS_Q + 32 * hh + lk * 8];
      f32x4 s[8];
#pragma unroll
      for (int qt = 0; qt < 8; ++qt) {
        s[qt] = zf;
        short8 bh = z8;
        if (l < 32)
          bh = *(const short8*)&qhi_s[(qt * 16 + lm) * TS_Q + 32 * hh + 16 + lk * 8];
        s[qt] = MFMA(ah, bh, s[qt]);
      }
#pragma unroll
      for (int r = 0; r < 4; ++r) {
        float e[8], sum = 0.f;
#pragma unroll
        for (int qt = 0; qt < 8; ++qt) { e[qt] = exp2f(s[qt][r]); sum += e[qt]; }
        sum += __shfl_xor(sum, 1);
        sum += __shfl_xor(sum, 2);
        sum += __shfl_xor(sum, 4);
        sum += __shfl_xor(sum, 8);
        float inv = __builtin_amdgcn_rcpf(sum);
#pragma unroll
        for (int qt = 0; qt < 8; ++qt) aacc[r][qt] += e[qt] * inv;
      }
    }
    __syncthreads();  // Q reads done before next proj overwrites qhi_s
    short* t = wcur; wcur = wnxt; wnxt = t;
  }

  // ---- elementwise finish: m_c = (abar/8) * z, exact fp32 z from global ----
#pragma unroll
  for (int r = 0; r < 4; ++r) {
    int cc = w * 16 + lk * 4 + r;
    const float* zrow = qz + ((size_t)(b * NC + cc) * NP + p) * ND;
    float* orow = out + ((size_t)(b * NC + cc) * NP + p) * ND;
#pragma unroll
    for (int qt = 0; qt < 8; ++qt) {
      int d = qt * 16 + lm;
      orow[d] = 0.125f * aacc[r][qt] * zrow[d];
    }
  }
}

// ================= fused dispatcher =================
// (512,3): VGPR cap 85 (R15/R16 verified); LDS 53,760 -> 3 blocks/CU.
template <int WS>
__global__ __launch_bounds__(512, 3)
void fused_kernel(const float* __restrict__ qz, const float* __restrict__ tuw,
                  const float* __restrict__ tvw, const float* __restrict__ cuw,
                  const float* __restrict__ cvw, const short* __restrict__ whi,
                  const short* __restrict__ wlo, float* __restrict__ out_t,
                  float* __restrict__ out_c) {
  __shared__ __align__(16) short smem[26880];  // 53,760 B
  const int bid = blockIdx.x;
  const int r7 = bid % 7, q7 = bid / 7;
  if (r7 < 4)
    tmsg_body<WS>(q7 * 4 + r7, qz, tuw, tvw, whi, wlo, out_t, smem);
  else
    cmsg_body<WS>(q7 * 3 + (r7 - 4), qz, cuw, cvw, whi, wlo, out_c, smem);
}

extern "C" void kernel_launch(void* const* d_in, const int* in_sizes, int n_in,
                              void* d_out, int out_size, void* d_ws, size_t ws_size,
                              hipStream_t stream) {
  const float* qz  = (const float*)d_in[0];
  const float* tuw = (const float*)d_in[1];
  const float* tvw = (const float*)d_in[2];
  const float* cuw = (const float*)d_in[3];
  const float* cvw = (const float*)d_in[4];
  float* out_t = (float*)d_out;
  float* out_c = out_t + (size_t)NB * NC * NP * ND;

  if (ws_size >= W_NEED) {
    short* whi = (short*)d_ws;
    short* wlo = whi + W_ELEMS;
    prep_w<<<256, 256, 0, stream>>>(tuw, tvw, cuw, cvw, whi, wlo);
    fused_kernel<1><<<1792, 512, 0, stream>>>(qz, tuw, tvw, cuw, cvw, whi, wlo,
                                              out_t, out_c);
  } else {
    fused_kernel<0><<<1792, 512, 0, stream>>>(qz, tuw, tvw, cuw, cvw, nullptr,
                                              nullptr, out_t, out_c);
  }
}